// Round 5
// baseline (666.912 us; speedup 1.0000x reference)
//
#include <hip/hip_runtime.h>
#include <math.h>

#define B_DIM 2048
#define D_DIM 512
#define F_DIM 16384
#define K_TOP 3

typedef __attribute__((ext_vector_type(8))) short bf16x8;
typedef __attribute__((ext_vector_type(4))) float f32x4;

// lexicographic "better": larger value wins; tie -> lower index (lax.top_k)
__device__ __forceinline__ bool better(float v, int c, float w, int j) {
    return (v > w) || (v == w && c < j);
}

__device__ __forceinline__ void ins3(float v, int c,
    float& v0, int& i0, float& v1, int& i1, float& v2, int& i2)
{
    if (!better(v, c, v2, i2)) return;
    if (better(v, c, v1, i1)) {
        v2 = v1; i2 = i1;
        if (better(v, c, v0, i0)) { v1 = v0; i1 = i0; v0 = v; i0 = c; }
        else { v1 = v; i1 = c; }
    } else { v2 = v; i2 = c; }
}

template <int N>
__device__ __forceinline__ void insN(float v, int c, float* V, int* I) {
#pragma unroll
    for (int k = 0; k < N; ++k) {
        bool b = better(v, c, V[k], I[k]);
        float tv = V[k]; int ti = I[k];
        if (b) { V[k] = v; I[k] = c; v = tv; c = ti; }
    }
}

// ---------------------------------------------------------------------------
// Kernel 0: f32 -> bf16 (truncation), 8 elems/thread/iter
// ---------------------------------------------------------------------------
__global__ __launch_bounds__(256) void convert_kernel(
    const float* __restrict__ src, ushort* __restrict__ dst, int n8)
{
    int i = blockIdx.x * 256 + threadIdx.x;
    const int stride = gridDim.x * 256;
    for (; i < n8; i += stride) {
        float4 a = ((const float4*)src)[i * 2];
        float4 b = ((const float4*)src)[i * 2 + 1];
        uint4 o;
        o.x = (__float_as_uint(a.y) & 0xFFFF0000u) | (__float_as_uint(a.x) >> 16);
        o.y = (__float_as_uint(a.w) & 0xFFFF0000u) | (__float_as_uint(a.z) >> 16);
        o.z = (__float_as_uint(b.y) & 0xFFFF0000u) | (__float_as_uint(b.x) >> 16);
        o.w = (__float_as_uint(b.w) & 0xFFFF0000u) | (__float_as_uint(b.z) >> 16);
        ((uint4*)dst)[i] = o;
    }
}

// ---------------------------------------------------------------------------
// Kernel 1: bf16 MFMA GEMM pre = x @ We^T (+be), fused per-(row, 64-col-half)
// top-3 screen. 128x128 tile, BK=32, 4 waves (2x2).
// REG-STAGED double buffer (no global_load_lds): loads for tile t+1 issued a
// full tile ahead into named register slots (E/O), ds_write_b128 after the
// MFMAs (compiler emits a counted vmcnt for just that slot; next tile's loads
// stay in flight across the barrier). K-loop unrolled x2 => static buffers.
// LDS row-major [128][32] bf16 with granule-XOR swizzle key=(row>>1)&3 on the
// ds_write address and the ds_read_b128 fragment address (0 conflicts, R4).
// ---------------------------------------------------------------------------
__global__ __launch_bounds__(256) void enc_mfma_kernel(
    const ushort* __restrict__ xb, const ushort* __restrict__ web,
    const float* __restrict__ be, uint* __restrict__ packed)
{
    __shared__ __align__(16) ushort As[2][4096];   // [buf][row*32 + k]
    __shared__ __align__(16) ushort Bs[2][4096];

    const int t = threadIdx.x;
    const int l = t & 63;
    const int w = t >> 6;
    const int wr = w >> 1, wc = w & 1;
    const int bm0 = blockIdx.y << 7;
    const int fn0 = blockIdx.x << 7;
    const int frow = l & 15;      // fragment row/col lane part
    const int q = l >> 4;         // k-chunk of fragment (0..3)

    // staging geometry: lane t covers LDS row t>>2 (and +64), granule t&3
    const int srow = t >> 2;                  // 0..63
    const int sg = t & 3;                     // linear global granule
    const int wsg = sg ^ ((srow >> 1) & 3);   // swizzled LDS granule
    const ushort* gA0 = xb + (size_t)(bm0 + srow) * D_DIM + sg * 8;
    const ushort* gA1 = gA0 + (size_t)64 * D_DIM;
    const ushort* gB0 = web + (size_t)(fn0 + srow) * D_DIM + sg * 8;
    const ushort* gB1 = gB0 + (size_t)64 * D_DIM;
    char* wA = (char*)&As[0][0] + srow * 64 + wsg * 16;   // +4096 for rows 64..127
    char* wB = (char*)&Bs[0][0] + srow * 64 + wsg * 16;

    // fragment read base (bytes): row-major + granule swizzle
    const int rk = (q ^ ((frow >> 1) & 3)) << 4;
    const char* rA = (const char*)&As[0][0] + (wr * 64 + frow) * 64 + rk;
    const char* rB = (const char*)&Bs[0][0] + (wc * 64 + frow) * 64 + rk;

    f32x4 acc[4][4];
#pragma unroll
    for (int m = 0; m < 4; ++m)
#pragma unroll
        for (int n = 0; n < 4; ++n) acc[m][n] = (f32x4)(0.f);

    uint4 eA0, eA1, eB0, eB1;   // even-tile slot
    uint4 oA0, oA1, oB0, oB1;   // odd-tile slot

#define LOADS_E(koff) do { eA0 = *(const uint4*)(gA0 + (koff)); \
    eA1 = *(const uint4*)(gA1 + (koff)); \
    eB0 = *(const uint4*)(gB0 + (koff)); \
    eB1 = *(const uint4*)(gB1 + (koff)); } while (0)
#define LOADS_O(koff) do { oA0 = *(const uint4*)(gA0 + (koff)); \
    oA1 = *(const uint4*)(gA1 + (koff)); \
    oB0 = *(const uint4*)(gB0 + (koff)); \
    oB1 = *(const uint4*)(gB1 + (koff)); } while (0)
#define WRITES_E(bufbyte) do { *(uint4*)(wA + (bufbyte)) = eA0; \
    *(uint4*)(wA + (bufbyte) + 4096) = eA1; \
    *(uint4*)(wB + (bufbyte)) = eB0; \
    *(uint4*)(wB + (bufbyte) + 4096) = eB1; } while (0)
#define WRITES_O(bufbyte) do { *(uint4*)(wA + (bufbyte)) = oA0; \
    *(uint4*)(wA + (bufbyte) + 4096) = oA1; \
    *(uint4*)(wB + (bufbyte)) = oB0; \
    *(uint4*)(wB + (bufbyte) + 4096) = oB1; } while (0)
#define FRAGS_MFMA(bufbyte) do { \
    bf16x8 af[4], bfr[4]; \
    af[0] = *(const bf16x8*)(rA + (bufbyte)); \
    af[1] = *(const bf16x8*)(rA + (bufbyte) + 1024); \
    af[2] = *(const bf16x8*)(rA + (bufbyte) + 2048); \
    af[3] = *(const bf16x8*)(rA + (bufbyte) + 3072); \
    bfr[0] = *(const bf16x8*)(rB + (bufbyte)); \
    bfr[1] = *(const bf16x8*)(rB + (bufbyte) + 1024); \
    bfr[2] = *(const bf16x8*)(rB + (bufbyte) + 2048); \
    bfr[3] = *(const bf16x8*)(rB + (bufbyte) + 3072); \
    _Pragma("unroll") \
    for (int m = 0; m < 4; ++m) \
        _Pragma("unroll") \
        for (int n = 0; n < 4; ++n) \
            acc[m][n] = __builtin_amdgcn_mfma_f32_16x16x32_bf16( \
                af[m], bfr[n], acc[m][n], 0, 0, 0); } while (0)

    // prologue: tile0 -> buf0; tile1 loads in flight
    LOADS_E(0);
    WRITES_E(0);            // counted vmcnt on slot E only
    LOADS_O(32);
    __syncthreads();        // buf0 visible

    for (int kk = 0; kk < 8; ++kk) {
        const int kO = kk * 64 + 32;
        // --- even tile (2kk) from buf0 ---
        int kE2 = kO + 32; kE2 = kE2 > 480 ? 480 : kE2;
        LOADS_E(kE2);                 // tile 2kk+2, in flight
        FRAGS_MFMA(0);                // compute buf0
        WRITES_O(8192);               // waits slot O only (tile 2kk+1)
        __syncthreads();              // buf1 visible
        // --- odd tile (2kk+1) from buf1 ---
        int kO2 = kO + 64; kO2 = kO2 > 480 ? 480 : kO2;
        LOADS_O(kO2);                 // tile 2kk+3, in flight
        FRAGS_MFMA(8192);             // compute buf1
        WRITES_E(0);                  // waits slot E only
        __syncthreads();              // buf0 visible
    }
#undef LOADS_E
#undef LOADS_O
#undef WRITES_E
#undef WRITES_O
#undef FRAGS_MFMA

    float bias[4];
#pragma unroll
    for (int n = 0; n < 4; ++n) bias[n] = be[fn0 + wc * 64 + n * 16 + frow];

    const int rowbase = bm0 + wr * 64 + (q << 2);
    const int tile2 = (blockIdx.x << 1) + wc;

    // per-(row, 64-col-half) top-3: per-lane over n, then merge 16 col-lanes
#pragma unroll
    for (int m = 0; m < 4; ++m) {
#pragma unroll
        for (int i = 0; i < 4; ++i) {
            float v0 = -INFINITY, v1 = -INFINITY, v2 = -INFINITY;
            int i0 = 0x7fffffff, i1 = 0x7fffffff, i2 = 0x7fffffff;
#pragma unroll
            for (int n = 0; n < 4; ++n) {
                float v = acc[m][n][i] + bias[n];
                int c = wc * 64 + n * 16 + frow;   // local col in [0,128)
                ins3(v, c, v0, i0, v1, i1, v2, i2);
            }
#pragma unroll
            for (int mk = 1; mk <= 8; mk <<= 1) {
                float w0 = __shfl_xor(v0, mk), w1 = __shfl_xor(v1, mk), w2 = __shfl_xor(v2, mk);
                int   j0 = __shfl_xor(i0, mk), j1 = __shfl_xor(i1, mk), j2 = __shfl_xor(i2, mk);
                ins3(w0, j0, v0, i0, v1, i1, v2, i2);
                ins3(w1, j1, v0, i0, v1, i1, v2, i2);
                ins3(w2, j2, v0, i0, v1, i1, v2, i2);
            }
            if (frow == 0) {
                uint* dp = packed + (size_t)(rowbase + m * 16 + i) * 768 + tile2 * 3;
                dp[0] = (__float_as_uint(v0) & 0xFFFFFF80u) | (uint)i0;
                dp[1] = (__float_as_uint(v1) & 0xFFFFFF80u) | (uint)i1;
                dp[2] = (__float_as_uint(v2) & 0xFFFFFF80u) | (uint)i2;
            }
        }
    }
}

// ---------------------------------------------------------------------------
// Kernel 2: merge 256 half-tiles x 3 packed -> global top-8 candidates/row
// ---------------------------------------------------------------------------
__global__ __launch_bounds__(64) void topk8_merge_kernel(
    const uint* __restrict__ packed, int* __restrict__ c8i)
{
    const int row = blockIdx.x;
    const int l = threadIdx.x;
    float V[8]; int I[8];
#pragma unroll
    for (int j = 0; j < 8; ++j) { V[j] = -INFINITY; I[j] = 0x7fffffff; }
    const uint* p = packed + (size_t)row * 768;
#pragma unroll
    for (int m = 0; m < 12; ++m) {
        int pos = l + (m << 6);
        uint u = p[pos];
        float v = __uint_as_float(u & 0xFFFFFF80u);
        int tile2 = pos / 3;
        int gidx = ((tile2 >> 1) << 7) | (int)(u & 0x7Fu);
        insN<8>(v, gidx, V, I);
    }
#pragma unroll
    for (int mk = 1; mk < 64; mk <<= 1) {
        float wv[8]; int wi[8];
#pragma unroll
        for (int j = 0; j < 8; ++j) { wv[j] = __shfl_xor(V[j], mk); wi[j] = __shfl_xor(I[j], mk); }
#pragma unroll
        for (int j = 0; j < 8; ++j) insN<8>(wv[j], wi[j], V, I);
    }
    if (l == 0) {
#pragma unroll
        for (int j = 0; j < 8; ++j) c8i[row * 8 + j] = I[j];
    }
}

// ---------------------------------------------------------------------------
// Kernel 3: exact f32 refinement of the 8 candidates + lex top-3 select
// ---------------------------------------------------------------------------
__global__ __launch_bounds__(512) void refine_kernel(
    const float* __restrict__ x, const float* __restrict__ We,
    const float* __restrict__ be, const int* __restrict__ c8i,
    float* __restrict__ vals, int* __restrict__ idxv)
{
    const int row = blockIdx.x;
    const int wv = threadIdx.x >> 6, l = threadIdx.x & 63;
    const int f = c8i[row * 8 + wv];
    const float* xr = x + (size_t)row * D_DIM;
    const float* wp = We + (size_t)f * D_DIM;
    float s = 0.f;
#pragma unroll
    for (int m = 0; m < 8; ++m) { int e = l + (m << 6); s = fmaf(xr[e], wp[e], s); }
#pragma unroll
    for (int mk = 1; mk < 64; mk <<= 1) s += __shfl_xor(s, mk);
    __shared__ float sv[8];
    __shared__ int si[8];
    if (l == 0) { sv[wv] = s + be[f]; si[wv] = f; }
    __syncthreads();
    if (threadIdx.x == 0) {
        float v0 = -INFINITY, v1 = -INFINITY, v2 = -INFINITY;
        int i0 = 0x7fffffff, i1 = 0x7fffffff, i2 = 0x7fffffff;
        for (int k = 0; k < 8; ++k) ins3(sv[k], si[k], v0, i0, v1, i1, v2, i2);
        vals[row * 3 + 0] = v0; idxv[row * 3 + 0] = i0;
        vals[row * 3 + 1] = v1; idxv[row * 3 + 1] = i1;
        vals[row * 3 + 2] = v2; idxv[row * 3 + 2] = i2;
    }
}

// ---------------------------------------------------------------------------
// Kernel 4: tiled transpose+convert Wd/Wd1/Wd2 [D,F] f32 -> [F,D] bf16
// ---------------------------------------------------------------------------
__global__ __launch_bounds__(256) void transpose_bf_kernel(
    const float* __restrict__ Wd, const float* __restrict__ Wd1,
    const float* __restrict__ Wd2, ushort* __restrict__ WdT,
    ushort* __restrict__ Wd1T, ushort* __restrict__ Wd2T)
{
    __shared__ float tile[64][65];
    const int zi = blockIdx.z;
    const float* src = zi == 0 ? Wd : (zi == 1 ? Wd1 : Wd2);
    ushort* dst = zi == 0 ? WdT : (zi == 1 ? Wd1T : Wd2T);
    const int f0 = blockIdx.x << 6;
    const int d0 = blockIdx.y << 6;
    const int t = threadIdx.x;
#pragma unroll
    for (int it = 0; it < 16; ++it) {
        int idx = it * 256 + t;
        int dl = idx >> 6, fl = idx & 63;
        tile[dl][fl] = src[(size_t)(d0 + dl) * F_DIM + f0 + fl];
    }
    __syncthreads();
#pragma unroll
    for (int it = 0; it < 16; ++it) {
        int idx = it * 256 + t;
        int fl = idx >> 6, dl = idx & 63;
        dst[(size_t)(f0 + fl) * D_DIM + d0 + dl] =
            (ushort)(__float_as_uint(tile[dl][fl]) >> 16);
    }
}

// ---------------------------------------------------------------------------
// Kernel 5: Gram vectors pp, p1, p2, s11, s22 over all F (coalesced in f)
// ---------------------------------------------------------------------------
__global__ __launch_bounds__(256) void gram_kernel(
    const float* __restrict__ Wd, const float* __restrict__ Wd1,
    const float* __restrict__ Wd2, float* __restrict__ gram)
{
    const int f = blockIdx.x * 256 + threadIdx.x;
    float pp = 0, p1 = 0, p2 = 0, s11 = 0, s22 = 0;
    for (int dd = 0; dd < D_DIM; ++dd) {
        size_t off = (size_t)dd * F_DIM + f;
        float wd = Wd[off], w1 = Wd1[off], w2 = Wd2[off];
        pp  = fmaf(wd, wd, pp);
        p1  = fmaf(wd, w1, p1);
        p2  = fmaf(wd, w2, p2);
        s11 = fmaf(w1, w1, s11);
        s22 = fmaf(w2, w2, s22);
    }
    gram[f] = pp;
    gram[F_DIM + f] = p1;
    gram[2 * F_DIM + f] = p2;
    gram[3 * F_DIM + f] = s11;
    gram[4 * F_DIM + f] = s22;
}

// ---------------------------------------------------------------------------
// Kernel 6: per (b,k): child pre-acts (exact f32 dot), winner, c, flags
// ---------------------------------------------------------------------------
__global__ __launch_bounds__(256) void child_kernel(
    const float* __restrict__ x,
    const float* __restrict__ We1, const float* __restrict__ be1,
    const float* __restrict__ We2, const float* __restrict__ be2,
    const float* __restrict__ vals, const int* __restrict__ idxv,
    float* __restrict__ cvals, int* __restrict__ wflag,
    int* __restrict__ flagP, int* __restrict__ flag1, int* __restrict__ flag2)
{
    const int pair = (blockIdx.x << 2) + (threadIdx.x >> 6);
    const int lane = threadIdx.x & 63;
    const int b = pair / 3;
    const int f = idxv[pair];
    const float a = vals[pair];
    const float* xb = x + (size_t)b * D_DIM;
    const float* w1 = We1 + (size_t)f * D_DIM;
    const float* w2 = We2 + (size_t)f * D_DIM;
    float s1 = 0.f, s2 = 0.f;
#pragma unroll
    for (int m = 0; m < 8; ++m) {
        int e = lane + (m << 6);
        float xv = xb[e];
        s1 = fmaf(xv, w1[e], s1);
        s2 = fmaf(xv, w2[e], s2);
    }
#pragma unroll
    for (int m = 1; m < 64; m <<= 1) { s1 += __shfl_xor(s1, m); s2 += __shfl_xor(s2, m); }
    if (lane == 0) {
        float p1v = s1 + be1[f];
        float p2v = s2 + be2[f];
        float m1 = (a != 0.f) ? p1v : 0.f;
        float m2 = (a != 0.f) ? p2v : 0.f;
        bool win = m1 > m2;
        float fa1 = win ? m1 : 0.f;
        float fa2 = win ? 0.f : m2;
        cvals[pair] = win ? fa1 : fa2;
        wflag[pair] = win ? 1 : 0;
        flagP[f] = 1;
        if (fa1 != 0.f) flag1[f] = 1;
        if (fa2 != 0.f) flag2[f] = 1;
    }
}

// ---------------------------------------------------------------------------
// Kernel 7: recon from transposed bf16 decoders (coalesced row reads)
// ---------------------------------------------------------------------------
__global__ __launch_bounds__(512) void recon_kernel(
    const ushort* __restrict__ WdT, const float* __restrict__ bd,
    const ushort* __restrict__ Wd1T, const float* __restrict__ bd1,
    const ushort* __restrict__ Wd2T, const float* __restrict__ bd2,
    const float* __restrict__ vals, const int* __restrict__ idxv,
    const float* __restrict__ cvals, const int* __restrict__ wflag,
    float* __restrict__ out)
{
    const int b = blockIdx.x;
    const int d = threadIdx.x;
    float o = bd[d] + bd1[d] + bd2[d];
#pragma unroll
    for (int k = 0; k < 3; ++k) {
        const int p = b * 3 + k;
        const int f = idxv[p];
        const float a = vals[p];
        const float c = cvals[p];
        const int win = wflag[p];
        const size_t off = (size_t)f * D_DIM + d;
        o = fmaf(a, __uint_as_float((uint)WdT[off] << 16), o);
        if (c != 0.f) {
            const ushort* wt = win ? Wd1T : Wd2T;
            o = fmaf(c, __uint_as_float((uint)wt[off] << 16), o);
        }
    }
    out[(size_t)b * D_DIM + d] = o;
}

// ---------------------------------------------------------------------------
// Kernel 8: aux cosine terms per pair; deterministic per-block partials
// ---------------------------------------------------------------------------
__global__ __launch_bounds__(256) void aux_kernel(
    const float* __restrict__ vals, const float* __restrict__ cvals,
    const int* __restrict__ wflag, const int* __restrict__ idxv,
    const float* __restrict__ gram,
    float* __restrict__ auxpart, float* __restrict__ cntpart)
{
    const int p = blockIdx.x * 256 + threadIdx.x;
    float term = 0.f, act = 0.f;
    {
        const float a = vals[p];
        const float c = cvals[p];
        const int win = wflag[p];
        const int f = idxv[p];
        const float pp = gram[f];
        const float pc = win ? gram[F_DIM + f] : gram[2 * F_DIM + f];
        const float cc = win ? gram[3 * F_DIM + f] : gram[4 * F_DIM + f];
        const float dot = a * (a * pp + c * pc);
        const float nx = fabsf(a) * sqrtf(pp);
        const float ny2 = a * a * pp + 2.f * a * c * pc + c * c * cc;
        const float ny = sqrtf(fmaxf(ny2, 0.f));
        const float cosv = dot / (fmaxf(nx, 1e-8f) * fmaxf(ny, 1e-8f));
        if (a > 0.f) { act = 1.f; term = fmaxf(0.f, 0.7f - cosv); }
    }
#pragma unroll
    for (int m = 1; m < 64; m <<= 1) { term += __shfl_xor(term, m); act += __shfl_xor(act, m); }
    __shared__ float st[2][4];
    const int w = threadIdx.x >> 6;
    if ((threadIdx.x & 63) == 0) { st[0][w] = term; st[1][w] = act; }
    __syncthreads();
    if (threadIdx.x == 0) {
        auxpart[blockIdx.x] = st[0][0] + st[0][1] + st[0][2] + st[0][3];
        cntpart[blockIdx.x] = st[1][0] + st[1][1] + st[1][2] + st[1][3];
    }
}

// ---------------------------------------------------------------------------
// Kernel 9: count flags, finish aux, write scalar outputs (as f32)
// ---------------------------------------------------------------------------
__global__ __launch_bounds__(256) void finalize_kernel(
    const int* __restrict__ flagP, const int* __restrict__ flag1,
    const int* __restrict__ flag2,
    const float* __restrict__ auxpart, const float* __restrict__ cntpart,
    float* __restrict__ out)
{
    const int t = threadIdx.x;
    int sp = 0, s1 = 0, s2 = 0;
    for (int f = t; f < F_DIM; f += 256) { sp += flagP[f]; s1 += flag1[f]; s2 += flag2[f]; }
#pragma unroll
    for (int m = 1; m < 64; m <<= 1) {
        sp += __shfl_xor(sp, m); s1 += __shfl_xor(s1, m); s2 += __shfl_xor(s2, m);
    }
    __shared__ int red[3][4];
    const int w = t >> 6;
    if ((t & 63) == 0) { red[0][w] = sp; red[1][w] = s1; red[2][w] = s2; }
    __syncthreads();
    if (t == 0) {
        float np_ = (float)(red[0][0] + red[0][1] + red[0][2] + red[0][3]);
        float n1_ = (float)(red[1][0] + red[1][1] + red[1][2] + red[1][3]);
        float n2_ = (float)(red[2][0] + red[2][1] + red[2][2] + red[2][3]);
        float asum = 0.f, acnt = 0.f;
        for (int i = 0; i < 24; ++i) { asum += auxpart[i]; acnt += cntpart[i]; }
        const size_t base = (size_t)B_DIM * D_DIM;
        out[base + 0] = np_;
        out[base + 1] = n1_;
        out[base + 2] = n2_;
        out[base + 3] = asum / (acnt + 1e-8f);
    }
}

extern "C" void kernel_launch(void* const* d_in, const int* in_sizes, int n_in,
                              void* d_out, int out_size, void* d_ws, size_t ws_size,
                              hipStream_t stream)
{
    (void)in_sizes; (void)n_in; (void)out_size; (void)ws_size;
    const float* x   = (const float*)d_in[0];
    const float* We  = (const float*)d_in[1];
    const float* be  = (const float*)d_in[2];
    const float* Wd  = (const float*)d_in[3];
    const float* bd  = (const float*)d_in[4];
    const float* We1 = (const float*)d_in[5];
    const float* be1 = (const float*)d_in[6];
    const float* Wd1 = (const float*)d_in[7];
    const float* bd1 = (const float*)d_in[8];
    const float* We2 = (const float*)d_in[9];
    const float* be2 = (const float*)d_in[10];
    const float* Wd2 = (const float*)d_in[11];
    const float* bd2 = (const float*)d_in[12];
    float* out = (float*)d_out;

    // workspace layout (16B aligned chunks), total ~76 MB
    ushort* x_bf  = (ushort*)d_ws;                             // B*D
    ushort* We_bf = x_bf + (size_t)B_DIM * D_DIM;              // F*D
    ushort* WdT   = We_bf + (size_t)F_DIM * D_DIM;             // F*D
    ushort* Wd1T  = WdT + (size_t)F_DIM * D_DIM;               // F*D
    ushort* Wd2T  = Wd1T + (size_t)F_DIM * D_DIM;              // F*D
    uint*   packed = (uint*)(Wd2T + (size_t)F_DIM * D_DIM);    // B*768
    float*  gram  = (float*)(packed + (size_t)B_DIM * 768);    // 5F
    int*    flagP = (int*)(gram + 5 * F_DIM);                  // F
    int*    flag1 = flagP + F_DIM;                             // F
    int*    flag2 = flag1 + F_DIM;                             // F
    int*    c8i   = flag2 + F_DIM;                             // B*8
    float*  vals  = (float*)(c8i + B_DIM * 8);                 // B*3
    int*    idxv  = (int*)(vals + B_DIM * 3);                  // B*3
    float*  cvals = (float*)(idxv + B_DIM * 3);                // B*3
    int*    wflag = (int*)(cvals + B_DIM * 3);                 // B*3
    float*  auxpart = (float*)(wflag + B_DIM * 3);             // 24
    float*  cntpart = auxpart + 24;                            // 24

    hipMemsetAsync(flagP, 0, 3 * F_DIM * sizeof(int), stream);

    convert_kernel<<<2048, 256, 0, stream>>>(We, We_bf, F_DIM * D_DIM / 8);
    convert_kernel<<<256, 256, 0, stream>>>(x, x_bf, B_DIM * D_DIM / 8);

    dim3 g1(F_DIM / 128, B_DIM / 128);  // 128 x 16
    enc_mfma_kernel<<<g1, 256, 0, stream>>>(x_bf, We_bf, be, packed);
    topk8_merge_kernel<<<B_DIM, 64, 0, stream>>>(packed, c8i);
    refine_kernel<<<B_DIM, 512, 0, stream>>>(x, We, be, c8i, vals, idxv);

    dim3 gt(F_DIM / 64, D_DIM / 64, 3);
    transpose_bf_kernel<<<gt, 256, 0, stream>>>(Wd, Wd1, Wd2, WdT, Wd1T, Wd2T);
    gram_kernel<<<F_DIM / 256, 256, 0, stream>>>(Wd, Wd1, Wd2, gram);
    child_kernel<<<(B_DIM * K_TOP) / 4, 256, 0, stream>>>(
        x, We1, be1, We2, be2, vals, idxv, cvals, wflag, flagP, flag1, flag2);
    recon_kernel<<<B_DIM, 512, 0, stream>>>(
        WdT, bd, Wd1T, bd1, Wd2T, bd2, vals, idxv, cvals, wflag, out);
    aux_kernel<<<(B_DIM * K_TOP) / 256, 256, 0, stream>>>(
        vals, cvals, wflag, idxv, gram, auxpart, cntpart);
    finalize_kernel<<<1, 256, 0, stream>>>(flagP, flag1, flag2, auxpart, cntpart, out);
}

// Round 6
// 430.483 us; speedup vs baseline: 1.5492x; 1.5492x over previous
//
#include <hip/hip_runtime.h>
#include <math.h>

#define B_DIM 2048
#define D_DIM 512
#define F_DIM 16384
#define K_TOP 3

typedef __attribute__((ext_vector_type(8))) short bf16x8;
typedef __attribute__((ext_vector_type(4))) float f32x4;

#define GL16(gsrc, ldst) \
  __builtin_amdgcn_global_load_lds( \
      (__attribute__((address_space(1))) const void*)(gsrc), \
      (__attribute__((address_space(3))) void*)(ldst), 16, 0, 0)

// lexicographic "better": larger value wins; tie -> lower index (lax.top_k)
__device__ __forceinline__ bool better(float v, int c, float w, int j) {
    return (v > w) || (v == w && c < j);
}

__device__ __forceinline__ void ins3(float v, int c,
    float& v0, int& i0, float& v1, int& i1, float& v2, int& i2)
{
    if (!better(v, c, v2, i2)) return;
    if (better(v, c, v1, i1)) {
        v2 = v1; i2 = i1;
        if (better(v, c, v0, i0)) { v1 = v0; i1 = i0; v0 = v; i0 = c; }
        else { v1 = v; i1 = c; }
    } else { v2 = v; i2 = c; }
}

template <int N>
__device__ __forceinline__ void insN(float v, int c, float* V, int* I) {
#pragma unroll
    for (int k = 0; k < N; ++k) {
        bool b = better(v, c, V[k], I[k]);
        float tv = V[k]; int ti = I[k];
        if (b) { V[k] = v; I[k] = c; v = tv; c = ti; }
    }
}

// ---------------------------------------------------------------------------
// Kernel 0: f32 -> bf16 (truncation), 8 elems/thread/iter
// ---------------------------------------------------------------------------
__global__ __launch_bounds__(256) void convert_kernel(
    const float* __restrict__ src, ushort* __restrict__ dst, int n8)
{
    int i = blockIdx.x * 256 + threadIdx.x;
    const int stride = gridDim.x * 256;
    for (; i < n8; i += stride) {
        float4 a = ((const float4*)src)[i * 2];
        float4 b = ((const float4*)src)[i * 2 + 1];
        uint4 o;
        o.x = (__float_as_uint(a.y) & 0xFFFF0000u) | (__float_as_uint(a.x) >> 16);
        o.y = (__float_as_uint(a.w) & 0xFFFF0000u) | (__float_as_uint(a.z) >> 16);
        o.z = (__float_as_uint(b.y) & 0xFFFF0000u) | (__float_as_uint(b.x) >> 16);
        o.w = (__float_as_uint(b.w) & 0xFFFF0000u) | (__float_as_uint(b.z) >> 16);
        ((uint4*)dst)[i] = o;
    }
}

// ---------------------------------------------------------------------------
// Kernel 1: PURE bf16 MFMA GEMM pre = x @ We^T + be, stored as bf16 [B][F].
// Exact R4 K-loop (GL16 staging, granule-XOR swizzle, 0 bank conflicts);
// epilogue is just bias-add + stores. No fused top-k (ablation).
// ---------------------------------------------------------------------------
__global__ __launch_bounds__(256) void gemm_kernel(
    const ushort* __restrict__ xb, const ushort* __restrict__ web,
    const float* __restrict__ be, ushort* __restrict__ pre)
{
    __shared__ __align__(16) ushort As[2][4096];   // [buf][row*32 + k]
    __shared__ __align__(16) ushort Bs[2][4096];

    const int t = threadIdx.x;
    const int l = t & 63;
    const int w = t >> 6;
    const int wr = w >> 1, wc = w & 1;
    const int bm0 = blockIdx.y << 7;
    const int fn0 = blockIdx.x << 7;
    const int frow = l & 15;      // fragment row/col lane part
    const int q = l >> 4;         // k-chunk of fragment (0..3)

    // staging: lane t covers LDS row t>>2, granule t&3 (linear dest), global
    // source granule XOR-swizzled within the 64B row window (coalesced).
    const int srow = t >> 2;                   // 0..63
    const int sgr = (t & 3) ^ ((t >> 3) & 3);  // swizzled granule
    const int soff = sgr << 3;
    const ushort* gA0 = xb + (size_t)(bm0 + srow) * D_DIM + soff;
    const ushort* gA1 = xb + (size_t)(bm0 + 64 + srow) * D_DIM + soff;
    const ushort* gB0 = web + (size_t)(fn0 + srow) * D_DIM + soff;
    const ushort* gB1 = web + (size_t)(fn0 + 64 + srow) * D_DIM + soff;

#define STAGE(bufp, koff) do { \
    GL16(gA0 + (koff), (char*)As + (bufp) * 8192 + t * 16); \
    GL16(gA1 + (koff), (char*)As + (bufp) * 8192 + 4096 + t * 16); \
    GL16(gB0 + (koff), (char*)Bs + (bufp) * 8192 + t * 16); \
    GL16(gB1 + (koff), (char*)Bs + (bufp) * 8192 + 4096 + t * 16); \
} while (0)

    f32x4 acc[4][4];
#pragma unroll
    for (int m = 0; m < 4; ++m)
#pragma unroll
        for (int n = 0; n < 4; ++n) acc[m][n] = (f32x4)(0.f);

    STAGE(0, 0);
    __syncthreads();

    // fragment read offset: row-major + granule swizzle q ^ ((frow>>1)&3)
    const int qs = (q ^ ((frow >> 1) & 3)) << 3;
    const int aoff = (wr * 64 + frow) * 32 + qs;
    const int boff = (wc * 64 + frow) * 32 + qs;

    int cur = 0;
    for (int t16 = 0; t16 < 16; ++t16) {
        const ushort* Ab = &As[0][0] + cur * 4096 + aoff;
        const ushort* Bb = &Bs[0][0] + cur * 4096 + boff;
        bf16x8 af[4], bfr[4];
#pragma unroll
        for (int m = 0; m < 4; ++m) af[m] = *(const bf16x8*)(Ab + m * 512);
#pragma unroll
        for (int n = 0; n < 4; ++n) bfr[n] = *(const bf16x8*)(Bb + n * 512);
        if (t16 < 15) STAGE(cur ^ 1, (t16 + 1) * 32);
#pragma unroll
        for (int m = 0; m < 4; ++m)
#pragma unroll
            for (int n = 0; n < 4; ++n)
                acc[m][n] = __builtin_amdgcn_mfma_f32_16x16x32_bf16(
                    af[m], bfr[n], acc[m][n], 0, 0, 0);
        __syncthreads();
        cur ^= 1;
    }
#undef STAGE

    float bias[4];
#pragma unroll
    for (int n = 0; n < 4; ++n) bias[n] = be[fn0 + wc * 64 + n * 16 + frow];

    // C/D layout: col = l&15 (frow), row = (l>>4)*4 + i
    const int rowb = bm0 + wr * 64 + (q << 2);
    const int colb = fn0 + wc * 64 + frow;
#pragma unroll
    for (int m = 0; m < 4; ++m)
#pragma unroll
        for (int n = 0; n < 4; ++n)
#pragma unroll
            for (int i = 0; i < 4; ++i) {
                float v = acc[m][n][i] + bias[n];
                pre[(size_t)(rowb + m * 16 + i) * F_DIM + colb + n * 16] =
                    (ushort)(__float_as_uint(v) >> 16);
            }
}

// ---------------------------------------------------------------------------
// Kernel 2: per-row top-8 screen over bf16 pre (1 wave per row)
// ---------------------------------------------------------------------------
__global__ __launch_bounds__(64) void screen_kernel(
    const ushort* __restrict__ pre, int* __restrict__ c8i)
{
    const int row = blockIdx.x;
    const int l = threadIdx.x;
    const uint4* p = (const uint4*)(pre + (size_t)row * F_DIM);
    float V[8]; int I[8];
#pragma unroll
    for (int j = 0; j < 8; ++j) { V[j] = -INFINITY; I[j] = 0x7fffffff; }
#pragma unroll 4
    for (int m = 0; m < 32; ++m) {
        const int pos = l + (m << 6);
        uint4 u = p[pos];
        const int base = pos << 3;
        uint wbits[4] = {u.x, u.y, u.z, u.w};
#pragma unroll
        for (int h = 0; h < 4; ++h) {
            float vlo = __uint_as_float(wbits[h] << 16);
            float vhi = __uint_as_float(wbits[h] & 0xFFFF0000u);
            int clo = base + h * 2, chi = base + h * 2 + 1;
            if (better(vlo, clo, V[7], I[7])) insN<8>(vlo, clo, V, I);
            if (better(vhi, chi, V[7], I[7])) insN<8>(vhi, chi, V, I);
        }
    }
#pragma unroll
    for (int mk = 1; mk < 64; mk <<= 1) {
        float wv[8]; int wi[8];
#pragma unroll
        for (int j = 0; j < 8; ++j) { wv[j] = __shfl_xor(V[j], mk); wi[j] = __shfl_xor(I[j], mk); }
#pragma unroll
        for (int j = 0; j < 8; ++j)
            if (better(wv[j], wi[j], V[7], I[7])) insN<8>(wv[j], wi[j], V, I);
    }
    if (l == 0) {
#pragma unroll
        for (int j = 0; j < 8; ++j) c8i[row * 8 + j] = I[j];
    }
}

// ---------------------------------------------------------------------------
// Kernel 3: exact f32 refinement of the 8 candidates + lex top-3 select
// ---------------------------------------------------------------------------
__global__ __launch_bounds__(512) void refine_kernel(
    const float* __restrict__ x, const float* __restrict__ We,
    const float* __restrict__ be, const int* __restrict__ c8i,
    float* __restrict__ vals, int* __restrict__ idxv)
{
    const int row = blockIdx.x;
    const int wv = threadIdx.x >> 6, l = threadIdx.x & 63;
    const int f = c8i[row * 8 + wv];
    const float* xr = x + (size_t)row * D_DIM;
    const float* wp = We + (size_t)f * D_DIM;
    float s = 0.f;
#pragma unroll
    for (int m = 0; m < 8; ++m) { int e = l + (m << 6); s = fmaf(xr[e], wp[e], s); }
#pragma unroll
    for (int mk = 1; mk < 64; mk <<= 1) s += __shfl_xor(s, mk);
    __shared__ float sv[8];
    __shared__ int si[8];
    if (l == 0) { sv[wv] = s + be[f]; si[wv] = f; }
    __syncthreads();
    if (threadIdx.x == 0) {
        float v0 = -INFINITY, v1 = -INFINITY, v2 = -INFINITY;
        int i0 = 0x7fffffff, i1 = 0x7fffffff, i2 = 0x7fffffff;
        for (int k = 0; k < 8; ++k) ins3(sv[k], si[k], v0, i0, v1, i1, v2, i2);
        vals[row * 3 + 0] = v0; idxv[row * 3 + 0] = i0;
        vals[row * 3 + 1] = v1; idxv[row * 3 + 1] = i1;
        vals[row * 3 + 2] = v2; idxv[row * 3 + 2] = i2;
    }
}

// ---------------------------------------------------------------------------
// Kernel 4: tiled transpose+convert Wd/Wd1/Wd2 [D,F] f32 -> [F,D] bf16
// ---------------------------------------------------------------------------
__global__ __launch_bounds__(256) void transpose_bf_kernel(
    const float* __restrict__ Wd, const float* __restrict__ Wd1,
    const float* __restrict__ Wd2, ushort* __restrict__ WdT,
    ushort* __restrict__ Wd1T, ushort* __restrict__ Wd2T)
{
    __shared__ float tile[64][65];
    const int zi = blockIdx.z;
    const float* src = zi == 0 ? Wd : (zi == 1 ? Wd1 : Wd2);
    ushort* dst = zi == 0 ? WdT : (zi == 1 ? Wd1T : Wd2T);
    const int f0 = blockIdx.x << 6;
    const int d0 = blockIdx.y << 6;
    const int t = threadIdx.x;
#pragma unroll
    for (int it = 0; it < 16; ++it) {
        int idx = it * 256 + t;
        int dl = idx >> 6, fl = idx & 63;
        tile[dl][fl] = src[(size_t)(d0 + dl) * F_DIM + f0 + fl];
    }
    __syncthreads();
#pragma unroll
    for (int it = 0; it < 16; ++it) {
        int idx = it * 256 + t;
        int fl = idx >> 6, dl = idx & 63;
        dst[(size_t)(f0 + fl) * D_DIM + d0 + dl] =
            (ushort)(__float_as_uint(tile[dl][fl]) >> 16);
    }
}

// ---------------------------------------------------------------------------
// Kernel 5: Gram vectors pp, p1, p2, s11, s22 over all F (coalesced in f)
// ---------------------------------------------------------------------------
__global__ __launch_bounds__(256) void gram_kernel(
    const float* __restrict__ Wd, const float* __restrict__ Wd1,
    const float* __restrict__ Wd2, float* __restrict__ gram)
{
    const int f = blockIdx.x * 256 + threadIdx.x;
    float pp = 0, p1 = 0, p2 = 0, s11 = 0, s22 = 0;
    for (int dd = 0; dd < D_DIM; ++dd) {
        size_t off = (size_t)dd * F_DIM + f;
        float wd = Wd[off], w1 = Wd1[off], w2 = Wd2[off];
        pp  = fmaf(wd, wd, pp);
        p1  = fmaf(wd, w1, p1);
        p2  = fmaf(wd, w2, p2);
        s11 = fmaf(w1, w1, s11);
        s22 = fmaf(w2, w2, s22);
    }
    gram[f] = pp;
    gram[F_DIM + f] = p1;
    gram[2 * F_DIM + f] = p2;
    gram[3 * F_DIM + f] = s11;
    gram[4 * F_DIM + f] = s22;
}

// ---------------------------------------------------------------------------
// Kernel 6: per (b,k): child pre-acts (exact f32 dot), winner, c, flags
// ---------------------------------------------------------------------------
__global__ __launch_bounds__(256) void child_kernel(
    const float* __restrict__ x,
    const float* __restrict__ We1, const float* __restrict__ be1,
    const float* __restrict__ We2, const float* __restrict__ be2,
    const float* __restrict__ vals, const int* __restrict__ idxv,
    float* __restrict__ cvals, int* __restrict__ wflag,
    int* __restrict__ flagP, int* __restrict__ flag1, int* __restrict__ flag2)
{
    const int pair = (blockIdx.x << 2) + (threadIdx.x >> 6);
    const int lane = threadIdx.x & 63;
    const int b = pair / 3;
    const int f = idxv[pair];
    const float a = vals[pair];
    const float* xb = x + (size_t)b * D_DIM;
    const float* w1 = We1 + (size_t)f * D_DIM;
    const float* w2 = We2 + (size_t)f * D_DIM;
    float s1 = 0.f, s2 = 0.f;
#pragma unroll
    for (int m = 0; m < 8; ++m) {
        int e = lane + (m << 6);
        float xv = xb[e];
        s1 = fmaf(xv, w1[e], s1);
        s2 = fmaf(xv, w2[e], s2);
    }
#pragma unroll
    for (int m = 1; m < 64; m <<= 1) { s1 += __shfl_xor(s1, m); s2 += __shfl_xor(s2, m); }
    if (lane == 0) {
        float p1v = s1 + be1[f];
        float p2v = s2 + be2[f];
        float m1 = (a != 0.f) ? p1v : 0.f;
        float m2 = (a != 0.f) ? p2v : 0.f;
        bool win = m1 > m2;
        float fa1 = win ? m1 : 0.f;
        float fa2 = win ? 0.f : m2;
        cvals[pair] = win ? fa1 : fa2;
        wflag[pair] = win ? 1 : 0;
        flagP[f] = 1;
        if (fa1 != 0.f) flag1[f] = 1;
        if (fa2 != 0.f) flag2[f] = 1;
    }
}

// ---------------------------------------------------------------------------
// Kernel 7: recon from transposed bf16 decoders (coalesced row reads)
// ---------------------------------------------------------------------------
__global__ __launch_bounds__(512) void recon_kernel(
    const ushort* __restrict__ WdT, const float* __restrict__ bd,
    const ushort* __restrict__ Wd1T, const float* __restrict__ bd1,
    const ushort* __restrict__ Wd2T, const float* __restrict__ bd2,
    const float* __restrict__ vals, const int* __restrict__ idxv,
    const float* __restrict__ cvals, const int* __restrict__ wflag,
    float* __restrict__ out)
{
    const int b = blockIdx.x;
    const int d = threadIdx.x;
    float o = bd[d] + bd1[d] + bd2[d];
#pragma unroll
    for (int k = 0; k < 3; ++k) {
        const int p = b * 3 + k;
        const int f = idxv[p];
        const float a = vals[p];
        const float c = cvals[p];
        const int win = wflag[p];
        const size_t off = (size_t)f * D_DIM + d;
        o = fmaf(a, __uint_as_float((uint)WdT[off] << 16), o);
        if (c != 0.f) {
            const ushort* wt = win ? Wd1T : Wd2T;
            o = fmaf(c, __uint_as_float((uint)wt[off] << 16), o);
        }
    }
    out[(size_t)b * D_DIM + d] = o;
}

// ---------------------------------------------------------------------------
// Kernel 8: aux cosine terms per pair; deterministic per-block partials
// ---------------------------------------------------------------------------
__global__ __launch_bounds__(256) void aux_kernel(
    const float* __restrict__ vals, const float* __restrict__ cvals,
    const int* __restrict__ wflag, const int* __restrict__ idxv,
    const float* __restrict__ gram,
    float* __restrict__ auxpart, float* __restrict__ cntpart)
{
    const int p = blockIdx.x * 256 + threadIdx.x;
    float term = 0.f, act = 0.f;
    {
        const float a = vals[p];
        const float c = cvals[p];
        const int win = wflag[p];
        const int f = idxv[p];
        const float pp = gram[f];
        const float pc = win ? gram[F_DIM + f] : gram[2 * F_DIM + f];
        const float cc = win ? gram[3 * F_DIM + f] : gram[4 * F_DIM + f];
        const float dot = a * (a * pp + c * pc);
        const float nx = fabsf(a) * sqrtf(pp);
        const float ny2 = a * a * pp + 2.f * a * c * pc + c * c * cc;
        const float ny = sqrtf(fmaxf(ny2, 0.f));
        const float cosv = dot / (fmaxf(nx, 1e-8f) * fmaxf(ny, 1e-8f));
        if (a > 0.f) { act = 1.f; term = fmaxf(0.f, 0.7f - cosv); }
    }
#pragma unroll
    for (int m = 1; m < 64; m <<= 1) { term += __shfl_xor(term, m); act += __shfl_xor(act, m); }
    __shared__ float st[2][4];
    const int w = threadIdx.x >> 6;
    if ((threadIdx.x & 63) == 0) { st[0][w] = term; st[1][w] = act; }
    __syncthreads();
    if (threadIdx.x == 0) {
        auxpart[blockIdx.x] = st[0][0] + st[0][1] + st[0][2] + st[0][3];
        cntpart[blockIdx.x] = st[1][0] + st[1][1] + st[1][2] + st[1][3];
    }
}

// ---------------------------------------------------------------------------
// Kernel 9: count flags, finish aux, write scalar outputs (as f32)
// ---------------------------------------------------------------------------
__global__ __launch_bounds__(256) void finalize_kernel(
    const int* __restrict__ flagP, const int* __restrict__ flag1,
    const int* __restrict__ flag2,
    const float* __restrict__ auxpart, const float* __restrict__ cntpart,
    float* __restrict__ out)
{
    const int t = threadIdx.x;
    int sp = 0, s1 = 0, s2 = 0;
    for (int f = t; f < F_DIM; f += 256) { sp += flagP[f]; s1 += flag1[f]; s2 += flag2[f]; }
#pragma unroll
    for (int m = 1; m < 64; m <<= 1) {
        sp += __shfl_xor(sp, m); s1 += __shfl_xor(s1, m); s2 += __shfl_xor(s2, m);
    }
    __shared__ int red[3][4];
    const int w = t >> 6;
    if ((t & 63) == 0) { red[0][w] = sp; red[1][w] = s1; red[2][w] = s2; }
    __syncthreads();
    if (t == 0) {
        float np_ = (float)(red[0][0] + red[0][1] + red[0][2] + red[0][3]);
        float n1_ = (float)(red[1][0] + red[1][1] + red[1][2] + red[1][3]);
        float n2_ = (float)(red[2][0] + red[2][1] + red[2][2] + red[2][3]);
        float asum = 0.f, acnt = 0.f;
        for (int i = 0; i < 24; ++i) { asum += auxpart[i]; acnt += cntpart[i]; }
        const size_t base = (size_t)B_DIM * D_DIM;
        out[base + 0] = np_;
        out[base + 1] = n1_;
        out[base + 2] = n2_;
        out[base + 3] = asum / (acnt + 1e-8f);
    }
}

extern "C" void kernel_launch(void* const* d_in, const int* in_sizes, int n_in,
                              void* d_out, int out_size, void* d_ws, size_t ws_size,
                              hipStream_t stream)
{
    (void)in_sizes; (void)n_in; (void)out_size; (void)ws_size;
    const float* x   = (const float*)d_in[0];
    const float* We  = (const float*)d_in[1];
    const float* be  = (const float*)d_in[2];
    const float* Wd  = (const float*)d_in[3];
    const float* bd  = (const float*)d_in[4];
    const float* We1 = (const float*)d_in[5];
    const float* be1 = (const float*)d_in[6];
    const float* Wd1 = (const float*)d_in[7];
    const float* bd1 = (const float*)d_in[8];
    const float* We2 = (const float*)d_in[9];
    const float* be2 = (const float*)d_in[10];
    const float* Wd2 = (const float*)d_in[11];
    const float* bd2 = (const float*)d_in[12];
    float* out = (float*)d_out;

    // workspace layout (~87 MB).
    // region1 (pre, 64 MiB) is dead after screen_kernel; WdT/Wd1T/Wd2T
    // (3x16 MiB) alias it — transpose runs strictly after screen on the
    // same stream.
    ushort* x_bf  = (ushort*)d_ws;                             // B*D
    ushort* We_bf = x_bf + (size_t)B_DIM * D_DIM;              // F*D
    ushort* pre   = We_bf + (size_t)F_DIM * D_DIM;             // B*F (64MiB)
    ushort* WdT   = pre;                                       // alias
    ushort* Wd1T  = WdT + (size_t)F_DIM * D_DIM;
    ushort* Wd2T  = Wd1T + (size_t)F_DIM * D_DIM;
    float*  gram  = (float*)(pre + (size_t)B_DIM * F_DIM);     // 5F
    int*    flagP = (int*)(gram + 5 * F_DIM);                  // F
    int*    flag1 = flagP + F_DIM;                             // F
    int*    flag2 = flag1 + F_DIM;                             // F
    int*    c8i   = flag2 + F_DIM;                             // B*8
    float*  vals  = (float*)(c8i + B_DIM * 8);                 // B*3
    int*    idxv  = (int*)(vals + B_DIM * 3);                  // B*3
    float*  cvals = (float*)(idxv + B_DIM * 3);                // B*3
    int*    wflag = (int*)(cvals + B_DIM * 3);                 // B*3
    float*  auxpart = (float*)(wflag + B_DIM * 3);             // 24
    float*  cntpart = auxpart + 24;                            // 24

    hipMemsetAsync(flagP, 0, 3 * F_DIM * sizeof(int), stream);

    convert_kernel<<<2048, 256, 0, stream>>>(We, We_bf, F_DIM * D_DIM / 8);
    convert_kernel<<<256, 256, 0, stream>>>(x, x_bf, B_DIM * D_DIM / 8);

    dim3 g1(F_DIM / 128, B_DIM / 128);  // 128 x 16
    gemm_kernel<<<g1, 256, 0, stream>>>(x_bf, We_bf, be, pre);
    screen_kernel<<<B_DIM, 64, 0, stream>>>(pre, c8i);
    refine_kernel<<<B_DIM, 512, 0, stream>>>(x, We, be, c8i, vals, idxv);

    dim3 gt(F_DIM / 64, D_DIM / 64, 3);
    transpose_bf_kernel<<<gt, 256, 0, stream>>>(Wd, Wd1, Wd2, WdT, Wd1T, Wd2T);
    gram_kernel<<<F_DIM / 256, 256, 0, stream>>>(Wd, Wd1, Wd2, gram);
    child_kernel<<<(B_DIM * K_TOP) / 4, 256, 0, stream>>>(
        x, We1, be1, We2, be2, vals, idxv, cvals, wflag, flagP, flag1, flag2);
    recon_kernel<<<B_DIM, 512, 0, stream>>>(
        WdT, bd, Wd1T, bd1, Wd2T, bd2, vals, idxv, cvals, wflag, out);
    aux_kernel<<<(B_DIM * K_TOP) / 256, 256, 0, stream>>>(
        vals, cvals, wflag, idxv, gram, auxpart, cntpart);
    finalize_kernel<<<1, 256, 0, stream>>>(flagP, flag1, flag2, auxpart, cntpart, out);
}

// Round 7
// 166.942 us; speedup vs baseline: 3.9949x; 2.5786x over previous
//
#include <hip/hip_runtime.h>
#include <math.h>

#define B_DIM 2048
#define D_DIM 512
#define F_DIM 16384
#define K_TOP 3

typedef __attribute__((ext_vector_type(8))) short bf16x8;
typedef __attribute__((ext_vector_type(4))) float f32x4;

#define GL16(gsrc, ldst) \
  __builtin_amdgcn_global_load_lds( \
      (__attribute__((address_space(1))) const void*)(gsrc), \
      (__attribute__((address_space(3))) void*)(ldst), 16, 0, 0)

// lexicographic "better": larger value wins; tie -> lower index (lax.top_k)
__device__ __forceinline__ bool better(float v, int c, float w, int j) {
    return (v > w) || (v == w && c < j);
}

__device__ __forceinline__ void ins3(float v, int c,
    float& v0, int& i0, float& v1, int& i1, float& v2, int& i2)
{
    if (!better(v, c, v2, i2)) return;
    if (better(v, c, v1, i1)) {
        v2 = v1; i2 = i1;
        if (better(v, c, v0, i0)) { v1 = v0; i1 = i0; v0 = v; i0 = c; }
        else { v1 = v; i1 = c; }
    } else { v2 = v; i2 = c; }
}

// monotonic u32 key: (ordered bf16 desc) then (col asc).  key>key' iff
// (bf16 val > val') or (val == val' and col < col').  30 bits used.
__device__ __forceinline__ uint okey(uint b16, int col) {
    uint m = 0x8000u + ((b16 >> 15) * 0x7FFFu);   // 0x8000 (+) / 0xFFFF (-)
    return ((b16 ^ m) << 14) | (uint)(16383 - col);
}

// branchless descending top-8 insert (umax/umin ladder)
__device__ __forceinline__ void insK8(uint k, uint* V) {
#pragma unroll
    for (int j = 0; j < 8; ++j) {
        uint hi = V[j] > k ? V[j] : k;
        uint lo = V[j] > k ? k : V[j];
        V[j] = hi; k = lo;
    }
}

// ---------------------------------------------------------------------------
// Kernel 0: f32 -> bf16 (truncation), 8 elems/thread/iter
// ---------------------------------------------------------------------------
__global__ __launch_bounds__(256) void convert_kernel(
    const float* __restrict__ src, ushort* __restrict__ dst, int n8)
{
    int i = blockIdx.x * 256 + threadIdx.x;
    const int stride = gridDim.x * 256;
    for (; i < n8; i += stride) {
        float4 a = ((const float4*)src)[i * 2];
        float4 b = ((const float4*)src)[i * 2 + 1];
        uint4 o;
        o.x = (__float_as_uint(a.y) & 0xFFFF0000u) | (__float_as_uint(a.x) >> 16);
        o.y = (__float_as_uint(a.w) & 0xFFFF0000u) | (__float_as_uint(a.z) >> 16);
        o.z = (__float_as_uint(b.y) & 0xFFFF0000u) | (__float_as_uint(b.x) >> 16);
        o.w = (__float_as_uint(b.w) & 0xFFFF0000u) | (__float_as_uint(b.z) >> 16);
        ((uint4*)dst)[i] = o;
    }
}

// ---------------------------------------------------------------------------
// Kernel 1: PURE bf16 MFMA GEMM pre = x @ We^T + be, stored as bf16 [B][F].
// (unchanged from R6 — verified fast)
// ---------------------------------------------------------------------------
__global__ __launch_bounds__(256) void gemm_kernel(
    const ushort* __restrict__ xb, const ushort* __restrict__ web,
    const float* __restrict__ be, ushort* __restrict__ pre)
{
    __shared__ __align__(16) ushort As[2][4096];   // [buf][row*32 + k]
    __shared__ __align__(16) ushort Bs[2][4096];

    const int t = threadIdx.x;
    const int l = t & 63;
    const int w = t >> 6;
    const int wr = w >> 1, wc = w & 1;
    const int bm0 = blockIdx.y << 7;
    const int fn0 = blockIdx.x << 7;
    const int frow = l & 15;
    const int q = l >> 4;

    const int srow = t >> 2;
    const int sgr = (t & 3) ^ ((t >> 3) & 3);
    const int soff = sgr << 3;
    const ushort* gA0 = xb + (size_t)(bm0 + srow) * D_DIM + soff;
    const ushort* gA1 = xb + (size_t)(bm0 + 64 + srow) * D_DIM + soff;
    const ushort* gB0 = web + (size_t)(fn0 + srow) * D_DIM + soff;
    const ushort* gB1 = web + (size_t)(fn0 + 64 + srow) * D_DIM + soff;

#define STAGE(bufp, koff) do { \
    GL16(gA0 + (koff), (char*)As + (bufp) * 8192 + t * 16); \
    GL16(gA1 + (koff), (char*)As + (bufp) * 8192 + 4096 + t * 16); \
    GL16(gB0 + (koff), (char*)Bs + (bufp) * 8192 + t * 16); \
    GL16(gB1 + (koff), (char*)Bs + (bufp) * 8192 + 4096 + t * 16); \
} while (0)

    f32x4 acc[4][4];
#pragma unroll
    for (int m = 0; m < 4; ++m)
#pragma unroll
        for (int n = 0; n < 4; ++n) acc[m][n] = (f32x4)(0.f);

    STAGE(0, 0);
    __syncthreads();

    const int qs = (q ^ ((frow >> 1) & 3)) << 3;
    const int aoff = (wr * 64 + frow) * 32 + qs;
    const int boff = (wc * 64 + frow) * 32 + qs;

    int cur = 0;
    for (int t16 = 0; t16 < 16; ++t16) {
        const ushort* Ab = &As[0][0] + cur * 4096 + aoff;
        const ushort* Bb = &Bs[0][0] + cur * 4096 + boff;
        bf16x8 af[4], bfr[4];
#pragma unroll
        for (int m = 0; m < 4; ++m) af[m] = *(const bf16x8*)(Ab + m * 512);
#pragma unroll
        for (int n = 0; n < 4; ++n) bfr[n] = *(const bf16x8*)(Bb + n * 512);
        if (t16 < 15) STAGE(cur ^ 1, (t16 + 1) * 32);
#pragma unroll
        for (int m = 0; m < 4; ++m)
#pragma unroll
            for (int n = 0; n < 4; ++n)
                acc[m][n] = __builtin_amdgcn_mfma_f32_16x16x32_bf16(
                    af[m], bfr[n], acc[m][n], 0, 0, 0);
        __syncthreads();
        cur ^= 1;
    }
#undef STAGE

    float bias[4];
#pragma unroll
    for (int n = 0; n < 4; ++n) bias[n] = be[fn0 + wc * 64 + n * 16 + frow];

    const int rowb = bm0 + wr * 64 + (q << 2);
    const int colb = fn0 + wc * 64 + frow;
#pragma unroll
    for (int m = 0; m < 4; ++m)
#pragma unroll
        for (int n = 0; n < 4; ++n)
#pragma unroll
            for (int i = 0; i < 4; ++i) {
                float v = acc[m][n][i] + bias[n];
                pre[(size_t)(rowb + m * 16 + i) * F_DIM + colb + n * 16] =
                    (ushort)(__float_as_uint(v) >> 16);
            }
}

// ---------------------------------------------------------------------------
// Kernel 2: per-row top-8 screen over bf16 pre. 4 waves/row, u32-key
// min/max ladders (branchless), snapshot butterfly merges.
// ---------------------------------------------------------------------------
__global__ __launch_bounds__(256) void screen_kernel(
    const ushort* __restrict__ pre, int* __restrict__ c8i)
{
    const int row = blockIdx.x;
    const int t = threadIdx.x;
    const int w = t >> 6, l = t & 63;
    const uint4* p = (const uint4*)(pre + (size_t)row * F_DIM) + w * 512 + l;
    uint V[8] = {0, 0, 0, 0, 0, 0, 0, 0};
#pragma unroll
    for (int k8 = 0; k8 < 8; ++k8) {
        uint4 u = p[k8 * 64];
        const int cb = (w * 512 + k8 * 64 + l) << 3;
        uint wb[4] = {u.x, u.y, u.z, u.w};
#pragma unroll
        for (int h = 0; h < 4; ++h) {
            uint klo = okey(wb[h] & 0xFFFFu, cb + h * 2);
            uint khi = okey(wb[h] >> 16, cb + h * 2 + 1);
            if (klo > V[7]) insK8(klo, V);
            if (khi > V[7]) insK8(khi, V);
        }
    }
    // butterfly merge across the wave (snapshot partner's 8 first)
#pragma unroll
    for (int mk = 1; mk < 64; mk <<= 1) {
        uint o[8];
#pragma unroll
        for (int j = 0; j < 8; ++j) o[j] = (uint)__shfl_xor((int)V[j], mk);
#pragma unroll
        for (int j = 0; j < 8; ++j)
            if (o[j] > V[7]) insK8(o[j], V);
    }
    __shared__ uint sh[32];
    if (l == 0) {
#pragma unroll
        for (int j = 0; j < 8; ++j) sh[w * 8 + j] = V[j];
    }
    __syncthreads();
    if (t < 64) {   // wave 0: merge 4x8 candidates
        uint V2[8] = {0, 0, 0, 0, 0, 0, 0, 0};
        if (t < 32) V2[0] = sh[t];
#pragma unroll
        for (int mk = 1; mk < 32; mk <<= 1) {
            uint o[8];
#pragma unroll
            for (int j = 0; j < 8; ++j) o[j] = (uint)__shfl_xor((int)V2[j], mk);
#pragma unroll
            for (int j = 0; j < 8; ++j)
                if (o[j] > V2[7]) insK8(o[j], V2);
        }
        if (t == 0) {
#pragma unroll
            for (int j = 0; j < 8; ++j)
                c8i[row * 8 + j] = 16383 - (int)(V2[j] & 16383u);
        }
    }
}

// ---------------------------------------------------------------------------
// Kernel 3: exact f32 refinement of the 8 candidates + lex top-3 select
// ---------------------------------------------------------------------------
__global__ __launch_bounds__(512) void refine_kernel(
    const float* __restrict__ x, const float* __restrict__ We,
    const float* __restrict__ be, const int* __restrict__ c8i,
    float* __restrict__ vals, int* __restrict__ idxv)
{
    const int row = blockIdx.x;
    const int wv = threadIdx.x >> 6, l = threadIdx.x & 63;
    const int f = c8i[row * 8 + wv];
    const float* xr = x + (size_t)row * D_DIM;
    const float* wp = We + (size_t)f * D_DIM;
    float s = 0.f;
#pragma unroll
    for (int m = 0; m < 8; ++m) { int e = l + (m << 6); s = fmaf(xr[e], wp[e], s); }
#pragma unroll
    for (int mk = 1; mk < 64; mk <<= 1) s += __shfl_xor(s, mk);
    __shared__ float sv[8];
    __shared__ int si[8];
    if (l == 0) { sv[wv] = s + be[f]; si[wv] = f; }
    __syncthreads();
    if (threadIdx.x == 0) {
        float v0 = -INFINITY, v1 = -INFINITY, v2 = -INFINITY;
        int i0 = 0x7fffffff, i1 = 0x7fffffff, i2 = 0x7fffffff;
        for (int k = 0; k < 8; ++k) ins3(sv[k], si[k], v0, i0, v1, i1, v2, i2);
        vals[row * 3 + 0] = v0; idxv[row * 3 + 0] = i0;
        vals[row * 3 + 1] = v1; idxv[row * 3 + 1] = i1;
        vals[row * 3 + 2] = v2; idxv[row * 3 + 2] = i2;
    }
}

// ---------------------------------------------------------------------------
// Kernel 4: FUSED transpose+gram. One 64-wide f-stripe per block over the
// full D; Gram sums accumulated in registers from the same loads that feed
// the transposed bf16 writes (saves a full 96 MB pass).
// ---------------------------------------------------------------------------
__global__ __launch_bounds__(512) void trgram_kernel(
    const float* __restrict__ Wd, const float* __restrict__ Wd1,
    const float* __restrict__ Wd2, ushort* __restrict__ WdT,
    ushort* __restrict__ Wd1T, ushort* __restrict__ Wd2T,
    float* __restrict__ gram)
{
    __shared__ float tA[64][65], tB[64][65], tC[64][65];
    __shared__ float gred[8][64][5];
    const int t = threadIdx.x;
    const int f0 = blockIdx.x << 6;
    const int wg = t >> 6;    // 0..7
    const int fl = t & 63;
    float pp = 0, p1 = 0, p2 = 0, s11 = 0, s22 = 0;

    for (int ch = 0; ch < 8; ++ch) {
        const int d0 = ch << 6;
        float a[8], b[8], c[8];
#pragma unroll
        for (int it = 0; it < 8; ++it) {
            int dl = (it << 3) + wg;
            size_t off = (size_t)(d0 + dl) * F_DIM + f0 + fl;
            a[it] = Wd[off]; b[it] = Wd1[off]; c[it] = Wd2[off];
        }
        if (ch) __syncthreads();   // prior write-phase reads done
#pragma unroll
        for (int it = 0; it < 8; ++it) {
            pp  = fmaf(a[it], a[it], pp);
            p1  = fmaf(a[it], b[it], p1);
            p2  = fmaf(a[it], c[it], p2);
            s11 = fmaf(b[it], b[it], s11);
            s22 = fmaf(c[it], c[it], s22);
            int dl = (it << 3) + wg;
            tA[dl][fl] = a[it]; tB[dl][fl] = b[it]; tC[dl][fl] = c[it];
        }
        __syncthreads();
#pragma unroll
        for (int it = 0; it < 8; ++it) {
            int flw = (it << 3) + wg, dlw = fl;
            size_t doff = (size_t)(f0 + flw) * D_DIM + d0 + dlw;
            WdT[doff]  = (ushort)(__float_as_uint(tA[dlw][flw]) >> 16);
            Wd1T[doff] = (ushort)(__float_as_uint(tB[dlw][flw]) >> 16);
            Wd2T[doff] = (ushort)(__float_as_uint(tC[dlw][flw]) >> 16);
        }
    }
    gred[wg][fl][0] = pp;  gred[wg][fl][1] = p1; gred[wg][fl][2] = p2;
    gred[wg][fl][3] = s11; gred[wg][fl][4] = s22;
    __syncthreads();
    if (t < 64) {
        float g0 = 0, g1 = 0, g2 = 0, g3 = 0, g4 = 0;
#pragma unroll
        for (int g = 0; g < 8; ++g) {
            g0 += gred[g][t][0]; g1 += gred[g][t][1]; g2 += gred[g][t][2];
            g3 += gred[g][t][3]; g4 += gred[g][t][4];
        }
        gram[f0 + t] = g0;
        gram[F_DIM + f0 + t] = g1;
        gram[2 * F_DIM + f0 + t] = g2;
        gram[3 * F_DIM + f0 + t] = g3;
        gram[4 * F_DIM + f0 + t] = g4;
    }
}

// ---------------------------------------------------------------------------
// Kernel 5: per (b,k): child pre-acts (exact f32 dot), winner, c, flags
// ---------------------------------------------------------------------------
__global__ __launch_bounds__(256) void child_kernel(
    const float* __restrict__ x,
    const float* __restrict__ We1, const float* __restrict__ be1,
    const float* __restrict__ We2, const float* __restrict__ be2,
    const float* __restrict__ vals, const int* __restrict__ idxv,
    float* __restrict__ cvals, int* __restrict__ wflag,
    int* __restrict__ flagP, int* __restrict__ flag1, int* __restrict__ flag2)
{
    const int pair = (blockIdx.x << 2) + (threadIdx.x >> 6);
    const int lane = threadIdx.x & 63;
    const int b = pair / 3;
    const int f = idxv[pair];
    const float a = vals[pair];
    const float* xb = x + (size_t)b * D_DIM;
    const float* w1 = We1 + (size_t)f * D_DIM;
    const float* w2 = We2 + (size_t)f * D_DIM;
    float s1 = 0.f, s2 = 0.f;
#pragma unroll
    for (int m = 0; m < 8; ++m) {
        int e = lane + (m << 6);
        float xv = xb[e];
        s1 = fmaf(xv, w1[e], s1);
        s2 = fmaf(xv, w2[e], s2);
    }
#pragma unroll
    for (int m = 1; m < 64; m <<= 1) { s1 += __shfl_xor(s1, m); s2 += __shfl_xor(s2, m); }
    if (lane == 0) {
        float p1v = s1 + be1[f];
        float p2v = s2 + be2[f];
        float m1 = (a != 0.f) ? p1v : 0.f;
        float m2 = (a != 0.f) ? p2v : 0.f;
        bool win = m1 > m2;
        float fa1 = win ? m1 : 0.f;
        float fa2 = win ? 0.f : m2;
        cvals[pair] = win ? fa1 : fa2;
        wflag[pair] = win ? 1 : 0;
        flagP[f] = 1;
        if (fa1 != 0.f) flag1[f] = 1;
        if (fa2 != 0.f) flag2[f] = 1;
    }
}

// ---------------------------------------------------------------------------
// Kernel 6: recon from transposed bf16 decoders (coalesced row reads)
// ---------------------------------------------------------------------------
__global__ __launch_bounds__(512) void recon_kernel(
    const ushort* __restrict__ WdT, const float* __restrict__ bd,
    const ushort* __restrict__ Wd1T, const float* __restrict__ bd1,
    const ushort* __restrict__ Wd2T, const float* __restrict__ bd2,
    const float* __restrict__ vals, const int* __restrict__ idxv,
    const float* __restrict__ cvals, const int* __restrict__ wflag,
    float* __restrict__ out)
{
    const int b = blockIdx.x;
    const int d = threadIdx.x;
    float o = bd[d] + bd1[d] + bd2[d];
#pragma unroll
    for (int k = 0; k < 3; ++k) {
        const int p = b * 3 + k;
        const int f = idxv[p];
        const float a = vals[p];
        const float c = cvals[p];
        const int win = wflag[p];
        const size_t off = (size_t)f * D_DIM + d;
        o = fmaf(a, __uint_as_float((uint)WdT[off] << 16), o);
        if (c != 0.f) {
            const ushort* wt = win ? Wd1T : Wd2T;
            o = fmaf(c, __uint_as_float((uint)wt[off] << 16), o);
        }
    }
    out[(size_t)b * D_DIM + d] = o;
}

// ---------------------------------------------------------------------------
// Kernel 7: aux cosine terms per pair; deterministic per-block partials
// ---------------------------------------------------------------------------
__global__ __launch_bounds__(256) void aux_kernel(
    const float* __restrict__ vals, const float* __restrict__ cvals,
    const int* __restrict__ wflag, const int* __restrict__ idxv,
    const float* __restrict__ gram,
    float* __restrict__ auxpart, float* __restrict__ cntpart)
{
    const int p = blockIdx.x * 256 + threadIdx.x;
    float term = 0.f, act = 0.f;
    {
        const float a = vals[p];
        const float c = cvals[p];
        const int win = wflag[p];
        const int f = idxv[p];
        const float pp = gram[f];
        const float pc = win ? gram[F_DIM + f] : gram[2 * F_DIM + f];
        const float cc = win ? gram[3 * F_DIM + f] : gram[4 * F_DIM + f];
        const float dot = a * (a * pp + c * pc);
        const float nx = fabsf(a) * sqrtf(pp);
        const float ny2 = a * a * pp + 2.f * a * c * pc + c * c * cc;
        const float ny = sqrtf(fmaxf(ny2, 0.f));
        const float cosv = dot / (fmaxf(nx, 1e-8f) * fmaxf(ny, 1e-8f));
        if (a > 0.f) { act = 1.f; term = fmaxf(0.f, 0.7f - cosv); }
    }
#pragma unroll
    for (int m = 1; m < 64; m <<= 1) { term += __shfl_xor(term, m); act += __shfl_xor(act, m); }
    __shared__ float st[2][4];
    const int w = threadIdx.x >> 6;
    if ((threadIdx.x & 63) == 0) { st[0][w] = term; st[1][w] = act; }
    __syncthreads();
    if (threadIdx.x == 0) {
        auxpart[blockIdx.x] = st[0][0] + st[0][1] + st[0][2] + st[0][3];
        cntpart[blockIdx.x] = st[1][0] + st[1][1] + st[1][2] + st[1][3];
    }
}

// ---------------------------------------------------------------------------
// Kernel 8: count flags, finish aux, write scalar outputs (as f32)
// ---------------------------------------------------------------------------
__global__ __launch_bounds__(256) void finalize_kernel(
    const int* __restrict__ flagP, const int* __restrict__ flag1,
    const int* __restrict__ flag2,
    const float* __restrict__ auxpart, const float* __restrict__ cntpart,
    float* __restrict__ out)
{
    const int t = threadIdx.x;
    int sp = 0, s1 = 0, s2 = 0;
    for (int f = t; f < F_DIM; f += 256) { sp += flagP[f]; s1 += flag1[f]; s2 += flag2[f]; }
#pragma unroll
    for (int m = 1; m < 64; m <<= 1) {
        sp += __shfl_xor(sp, m); s1 += __shfl_xor(s1, m); s2 += __shfl_xor(s2, m);
    }
    __shared__ int red[3][4];
    const int w = t >> 6;
    if ((t & 63) == 0) { red[0][w] = sp; red[1][w] = s1; red[2][w] = s2; }
    __syncthreads();
    if (t == 0) {
        float np_ = (float)(red[0][0] + red[0][1] + red[0][2] + red[0][3]);
        float n1_ = (float)(red[1][0] + red[1][1] + red[1][2] + red[1][3]);
        float n2_ = (float)(red[2][0] + red[2][1] + red[2][2] + red[2][3]);
        float asum = 0.f, acnt = 0.f;
        for (int i = 0; i < 24; ++i) { asum += auxpart[i]; acnt += cntpart[i]; }
        const size_t base = (size_t)B_DIM * D_DIM;
        out[base + 0] = np_;
        out[base + 1] = n1_;
        out[base + 2] = n2_;
        out[base + 3] = asum / (acnt + 1e-8f);
    }
}

extern "C" void kernel_launch(void* const* d_in, const int* in_sizes, int n_in,
                              void* d_out, int out_size, void* d_ws, size_t ws_size,
                              hipStream_t stream)
{
    (void)in_sizes; (void)n_in; (void)out_size; (void)ws_size;
    const float* x   = (const float*)d_in[0];
    const float* We  = (const float*)d_in[1];
    const float* be  = (const float*)d_in[2];
    const float* Wd  = (const float*)d_in[3];
    const float* bd  = (const float*)d_in[4];
    const float* We1 = (const float*)d_in[5];
    const float* be1 = (const float*)d_in[6];
    const float* Wd1 = (const float*)d_in[7];
    const float* bd1 = (const float*)d_in[8];
    const float* We2 = (const float*)d_in[9];
    const float* be2 = (const float*)d_in[10];
    const float* Wd2 = (const float*)d_in[11];
    const float* bd2 = (const float*)d_in[12];
    float* out = (float*)d_out;

    // workspace layout (~87 MB). pre (64 MiB) is dead after screen_kernel;
    // WdT/Wd1T/Wd2T alias it (trgram runs strictly after screen).
    ushort* x_bf  = (ushort*)d_ws;                             // B*D
    ushort* We_bf = x_bf + (size_t)B_DIM * D_DIM;              // F*D
    ushort* pre   = We_bf + (size_t)F_DIM * D_DIM;             // B*F (64MiB)
    ushort* WdT   = pre;                                       // alias
    ushort* Wd1T  = WdT + (size_t)F_DIM * D_DIM;
    ushort* Wd2T  = Wd1T + (size_t)F_DIM * D_DIM;
    float*  gram  = (float*)(pre + (size_t)B_DIM * F_DIM);     // 5F
    int*    flagP = (int*)(gram + 5 * F_DIM);                  // F
    int*    flag1 = flagP + F_DIM;                             // F
    int*    flag2 = flag1 + F_DIM;                             // F
    int*    c8i   = flag2 + F_DIM;                             // B*8
    float*  vals  = (float*)(c8i + B_DIM * 8);                 // B*3
    int*    idxv  = (int*)(vals + B_DIM * 3);                  // B*3
    float*  cvals = (float*)(idxv + B_DIM * 3);                // B*3
    int*    wflag = (int*)(cvals + B_DIM * 3);                 // B*3
    float*  auxpart = (float*)(wflag + B_DIM * 3);             // 24
    float*  cntpart = auxpart + 24;                            // 24

    hipMemsetAsync(flagP, 0, 3 * F_DIM * sizeof(int), stream);

    convert_kernel<<<2048, 256, 0, stream>>>(We, We_bf, F_DIM * D_DIM / 8);
    convert_kernel<<<256, 256, 0, stream>>>(x, x_bf, B_DIM * D_DIM / 8);

    dim3 g1(F_DIM / 128, B_DIM / 128);  // 128 x 16
    gemm_kernel<<<g1, 256, 0, stream>>>(x_bf, We_bf, be, pre);
    screen_kernel<<<B_DIM, 256, 0, stream>>>(pre, c8i);
    refine_kernel<<<B_DIM, 512, 0, stream>>>(x, We, be, c8i, vals, idxv);

    trgram_kernel<<<F_DIM / 64, 512, 0, stream>>>(
        Wd, Wd1, Wd2, WdT, Wd1T, Wd2T, gram);
    child_kernel<<<(B_DIM * K_TOP) / 4, 256, 0, stream>>>(
        x, We1, be1, We2, be2, vals, idxv, cvals, wflag, flagP, flag1, flag2);
    recon_kernel<<<B_DIM, 512, 0, stream>>>(
        WdT, bd, Wd1T, bd1, Wd2T, bd2, vals, idxv, cvals, wflag, out);
    aux_kernel<<<(B_DIM * K_TOP) / 256, 256, 0, stream>>>(
        vals, cvals, wflag, idxv, gram, auxpart, cntpart);
    finalize_kernel<<<1, 256, 0, stream>>>(flagP, flag1, flag2, auxpart, cntpart, out);
}

// Round 8
// 147.945 us; speedup vs baseline: 4.5078x; 1.1284x over previous
//
#include <hip/hip_runtime.h>
#include <math.h>

#define B_DIM 2048
#define D_DIM 512
#define F_DIM 16384
#define K_TOP 3

typedef __attribute__((ext_vector_type(8))) short bf16x8;
typedef __attribute__((ext_vector_type(4))) float f32x4;

#define GL16(gsrc, ldst) \
  __builtin_amdgcn_global_load_lds( \
      (__attribute__((address_space(1))) const void*)(gsrc), \
      (__attribute__((address_space(3))) void*)(ldst), 16, 0, 0)

// lexicographic "better": larger value wins; tie -> lower index (lax.top_k)
__device__ __forceinline__ bool better(float v, int c, float w, int j) {
    return (v > w) || (v == w && c < j);
}

__device__ __forceinline__ void ins3(float v, int c,
    float& v0, int& i0, float& v1, int& i1, float& v2, int& i2)
{
    if (!better(v, c, v2, i2)) return;
    if (better(v, c, v1, i1)) {
        v2 = v1; i2 = i1;
        if (better(v, c, v0, i0)) { v1 = v0; i1 = i0; v0 = v; i0 = c; }
        else { v1 = v; i1 = c; }
    } else { v2 = v; i2 = c; }
}

// monotonic u32 key: (ordered bf16 desc) then (col asc).  key>key' iff
// (bf16 val > val') or (val == val' and col < col').  30 bits used.
__device__ __forceinline__ uint okey(uint b16, int col) {
    uint m = 0x8000u + ((b16 >> 15) * 0x7FFFu);   // 0x8000 (+) / 0xFFFF (-)
    return ((b16 ^ m) << 14) | (uint)(16383 - col);
}

// branchless descending top-8 insert (umax/umin ladder)
__device__ __forceinline__ void insK8(uint k, uint* V) {
#pragma unroll
    for (int j = 0; j < 8; ++j) {
        uint hi = V[j] > k ? V[j] : k;
        uint lo = V[j] > k ? k : V[j];
        V[j] = hi; k = lo;
    }
}

// branchless descending top-3 insert on three scalars
__device__ __forceinline__ void insK3(uint k, uint& V0, uint& V1, uint& V2) {
    uint h0 = V0 > k ? V0 : k, l0 = V0 > k ? k : V0; V0 = h0; k = l0;
    uint h1 = V1 > k ? V1 : k, l1 = V1 > k ? k : V1; V1 = h1; k = l1;
    V2 = V2 > k ? V2 : k;
}

// ---------------------------------------------------------------------------
// Kernel 0: f32 -> bf16 (truncation), 8 elems/thread/iter
// ---------------------------------------------------------------------------
__global__ __launch_bounds__(256) void convert_kernel(
    const float* __restrict__ src, ushort* __restrict__ dst, int n8)
{
    int i = blockIdx.x * 256 + threadIdx.x;
    const int stride = gridDim.x * 256;
    for (; i < n8; i += stride) {
        float4 a = ((const float4*)src)[i * 2];
        float4 b = ((const float4*)src)[i * 2 + 1];
        uint4 o;
        o.x = (__float_as_uint(a.y) & 0xFFFF0000u) | (__float_as_uint(a.x) >> 16);
        o.y = (__float_as_uint(a.w) & 0xFFFF0000u) | (__float_as_uint(a.z) >> 16);
        o.z = (__float_as_uint(b.y) & 0xFFFF0000u) | (__float_as_uint(b.x) >> 16);
        o.w = (__float_as_uint(b.w) & 0xFFFF0000u) | (__float_as_uint(b.z) >> 16);
        ((uint4*)dst)[i] = o;
    }
}

// ---------------------------------------------------------------------------
// Kernel 1: bf16 MFMA GEMM pre = x @ We^T + be, FUSED branchless key top-3
// per (row, 64-col half): packed[row][tile2*3+j], tile2 = blockIdx.x*2+wc.
// K-loop identical to the verified R6/R7 kernel. No pre materialization.
// ---------------------------------------------------------------------------
__global__ __launch_bounds__(256) void gemm_kernel(
    const ushort* __restrict__ xb, const ushort* __restrict__ web,
    const float* __restrict__ be, uint* __restrict__ packed)
{
    __shared__ __align__(16) ushort As[2][4096];   // [buf][row*32 + k]
    __shared__ __align__(16) ushort Bs[2][4096];

    const int t = threadIdx.x;
    const int l = t & 63;
    const int w = t >> 6;
    const int wr = w >> 1, wc = w & 1;
    const int bm0 = blockIdx.y << 7;
    const int fn0 = blockIdx.x << 7;
    const int frow = l & 15;
    const int q = l >> 4;

    const int srow = t >> 2;
    const int sgr = (t & 3) ^ ((t >> 3) & 3);
    const int soff = sgr << 3;
    const ushort* gA0 = xb + (size_t)(bm0 + srow) * D_DIM + soff;
    const ushort* gA1 = xb + (size_t)(bm0 + 64 + srow) * D_DIM + soff;
    const ushort* gB0 = web + (size_t)(fn0 + srow) * D_DIM + soff;
    const ushort* gB1 = web + (size_t)(fn0 + 64 + srow) * D_DIM + soff;

#define STAGE(bufp, koff) do { \
    GL16(gA0 + (koff), (char*)As + (bufp) * 8192 + t * 16); \
    GL16(gA1 + (koff), (char*)As + (bufp) * 8192 + 4096 + t * 16); \
    GL16(gB0 + (koff), (char*)Bs + (bufp) * 8192 + t * 16); \
    GL16(gB1 + (koff), (char*)Bs + (bufp) * 8192 + 4096 + t * 16); \
} while (0)

    f32x4 acc[4][4];
#pragma unroll
    for (int m = 0; m < 4; ++m)
#pragma unroll
        for (int n = 0; n < 4; ++n) acc[m][n] = (f32x4)(0.f);

    STAGE(0, 0);
    __syncthreads();

    const int qs = (q ^ ((frow >> 1) & 3)) << 3;
    const int aoff = (wr * 64 + frow) * 32 + qs;
    const int boff = (wc * 64 + frow) * 32 + qs;

    int cur = 0;
    for (int t16 = 0; t16 < 16; ++t16) {
        const ushort* Ab = &As[0][0] + cur * 4096 + aoff;
        const ushort* Bb = &Bs[0][0] + cur * 4096 + boff;
        bf16x8 af[4], bfr[4];
#pragma unroll
        for (int m = 0; m < 4; ++m) af[m] = *(const bf16x8*)(Ab + m * 512);
#pragma unroll
        for (int n = 0; n < 4; ++n) bfr[n] = *(const bf16x8*)(Bb + n * 512);
        if (t16 < 15) STAGE(cur ^ 1, (t16 + 1) * 32);
#pragma unroll
        for (int m = 0; m < 4; ++m)
#pragma unroll
            for (int n = 0; n < 4; ++n)
                acc[m][n] = __builtin_amdgcn_mfma_f32_16x16x32_bf16(
                    af[m], bfr[n], acc[m][n], 0, 0, 0);
        __syncthreads();
        cur ^= 1;
    }
#undef STAGE

    float bias[4];
#pragma unroll
    for (int n = 0; n < 4; ++n) bias[n] = be[fn0 + wc * 64 + n * 16 + frow];

    // fused branchless top-3 epilogue.
    // C/D layout: col = frow, row = q*4 + i (within 16x16 frag m,n).
    const int colb = fn0 + wc * 64 + frow;          // + n*16
    const int rowbase = bm0 + wr * 64 + (q << 2);   // + m*16 + i
    const int tile2 = (blockIdx.x << 1) + wc;
#pragma unroll
    for (int m = 0; m < 4; ++m) {
#pragma unroll
        for (int i = 0; i < 4; ++i) {
            uint V0 = 0, V1 = 0, V2 = 0;
#pragma unroll
            for (int n = 0; n < 4; ++n) {
                float v = acc[m][n][i] + bias[n];
                uint key = okey(__float_as_uint(v) >> 16, colb + n * 16);
                insK3(key, V0, V1, V2);
            }
            // merge the 16 col-lanes of this row (xor masks 1,2,4,8)
#pragma unroll
            for (int mk = 1; mk <= 8; mk <<= 1) {
                uint o0 = (uint)__shfl_xor((int)V0, mk);
                uint o1 = (uint)__shfl_xor((int)V1, mk);
                uint o2 = (uint)__shfl_xor((int)V2, mk);
                insK3(o0, V0, V1, V2);
                insK3(o1, V0, V1, V2);
                insK3(o2, V0, V1, V2);
            }
            if (frow == 0) {
                uint* dp = packed + (size_t)(rowbase + m * 16 + i) * 768 + tile2 * 3;
                dp[0] = V0; dp[1] = V1; dp[2] = V2;
            }
        }
    }
}

// ---------------------------------------------------------------------------
// Kernel 2: merge 256 half-tiles x 3 keys -> top-8 candidate cols per row
// ---------------------------------------------------------------------------
__global__ __launch_bounds__(64) void merge_kernel(
    const uint* __restrict__ packed, int* __restrict__ c8i)
{
    const int row = blockIdx.x;
    const int l = threadIdx.x;
    const uint* p = packed + (size_t)row * 768;
    uint V[8] = {0, 0, 0, 0, 0, 0, 0, 0};
#pragma unroll
    for (int m = 0; m < 12; ++m) {
        uint k = p[l + (m << 6)];
        if (k > V[7]) insK8(k, V);
    }
#pragma unroll
    for (int mk = 1; mk < 64; mk <<= 1) {
        uint o[8];
#pragma unroll
        for (int j = 0; j < 8; ++j) o[j] = (uint)__shfl_xor((int)V[j], mk);
#pragma unroll
        for (int j = 0; j < 8; ++j)
            if (o[j] > V[7]) insK8(o[j], V);
    }
    if (l == 0) {
#pragma unroll
        for (int j = 0; j < 8; ++j)
            c8i[row * 8 + j] = 16383 - (int)(V[j] & 16383u);
    }
}

// ---------------------------------------------------------------------------
// Kernel 3: exact f32 refinement of the 8 candidates + lex top-3 select
// ---------------------------------------------------------------------------
__global__ __launch_bounds__(512) void refine_kernel(
    const float* __restrict__ x, const float* __restrict__ We,
    const float* __restrict__ be, const int* __restrict__ c8i,
    float* __restrict__ vals, int* __restrict__ idxv)
{
    const int row = blockIdx.x;
    const int wv = threadIdx.x >> 6, l = threadIdx.x & 63;
    const int f = c8i[row * 8 + wv];
    const float* xr = x + (size_t)row * D_DIM;
    const float* wp = We + (size_t)f * D_DIM;
    float s = 0.f;
#pragma unroll
    for (int m = 0; m < 8; ++m) { int e = l + (m << 6); s = fmaf(xr[e], wp[e], s); }
#pragma unroll
    for (int mk = 1; mk < 64; mk <<= 1) s += __shfl_xor(s, mk);
    __shared__ float sv[8];
    __shared__ int si[8];
    if (l == 0) { sv[wv] = s + be[f]; si[wv] = f; }
    __syncthreads();
    if (threadIdx.x == 0) {
        float v0 = -INFINITY, v1 = -INFINITY, v2 = -INFINITY;
        int i0 = 0x7fffffff, i1 = 0x7fffffff, i2 = 0x7fffffff;
        for (int k = 0; k < 8; ++k) ins3(sv[k], si[k], v0, i0, v1, i1, v2, i2);
        vals[row * 3 + 0] = v0; idxv[row * 3 + 0] = i0;
        vals[row * 3 + 1] = v1; idxv[row * 3 + 1] = i1;
        vals[row * 3 + 2] = v2; idxv[row * 3 + 2] = i2;
    }
}

// ---------------------------------------------------------------------------
// Kernel 4: FUSED transpose+gram (unchanged from R7)
// ---------------------------------------------------------------------------
__global__ __launch_bounds__(512) void trgram_kernel(
    const float* __restrict__ Wd, const float* __restrict__ Wd1,
    const float* __restrict__ Wd2, ushort* __restrict__ WdT,
    ushort* __restrict__ Wd1T, ushort* __restrict__ Wd2T,
    float* __restrict__ gram)
{
    __shared__ float tA[64][65], tB[64][65], tC[64][65];
    __shared__ float gred[8][64][5];
    const int t = threadIdx.x;
    const int f0 = blockIdx.x << 6;
    const int wg = t >> 6;    // 0..7
    const int fl = t & 63;
    float pp = 0, p1 = 0, p2 = 0, s11 = 0, s22 = 0;

    for (int ch = 0; ch < 8; ++ch) {
        const int d0 = ch << 6;
        float a[8], b[8], c[8];
#pragma unroll
        for (int it = 0; it < 8; ++it) {
            int dl = (it << 3) + wg;
            size_t off = (size_t)(d0 + dl) * F_DIM + f0 + fl;
            a[it] = Wd[off]; b[it] = Wd1[off]; c[it] = Wd2[off];
        }
        if (ch) __syncthreads();
#pragma unroll
        for (int it = 0; it < 8; ++it) {
            pp  = fmaf(a[it], a[it], pp);
            p1  = fmaf(a[it], b[it], p1);
            p2  = fmaf(a[it], c[it], p2);
            s11 = fmaf(b[it], b[it], s11);
            s22 = fmaf(c[it], c[it], s22);
            int dl = (it << 3) + wg;
            tA[dl][fl] = a[it]; tB[dl][fl] = b[it]; tC[dl][fl] = c[it];
        }
        __syncthreads();
#pragma unroll
        for (int it = 0; it < 8; ++it) {
            int flw = (it << 3) + wg, dlw = fl;
            size_t doff = (size_t)(f0 + flw) * D_DIM + d0 + dlw;
            WdT[doff]  = (ushort)(__float_as_uint(tA[dlw][flw]) >> 16);
            Wd1T[doff] = (ushort)(__float_as_uint(tB[dlw][flw]) >> 16);
            Wd2T[doff] = (ushort)(__float_as_uint(tC[dlw][flw]) >> 16);
        }
    }
    gred[wg][fl][0] = pp;  gred[wg][fl][1] = p1; gred[wg][fl][2] = p2;
    gred[wg][fl][3] = s11; gred[wg][fl][4] = s22;
    __syncthreads();
    if (t < 64) {
        float g0 = 0, g1 = 0, g2 = 0, g3 = 0, g4 = 0;
#pragma unroll
        for (int g = 0; g < 8; ++g) {
            g0 += gred[g][t][0]; g1 += gred[g][t][1]; g2 += gred[g][t][2];
            g3 += gred[g][t][3]; g4 += gred[g][t][4];
        }
        gram[f0 + t] = g0;
        gram[F_DIM + f0 + t] = g1;
        gram[2 * F_DIM + f0 + t] = g2;
        gram[3 * F_DIM + f0 + t] = g3;
        gram[4 * F_DIM + f0 + t] = g4;
    }
}

// ---------------------------------------------------------------------------
// Kernel 5: per (b,k): child pre-acts (exact f32 dot), winner, c, flags
// ---------------------------------------------------------------------------
__global__ __launch_bounds__(256) void child_kernel(
    const float* __restrict__ x,
    const float* __restrict__ We1, const float* __restrict__ be1,
    const float* __restrict__ We2, const float* __restrict__ be2,
    const float* __restrict__ vals, const int* __restrict__ idxv,
    float* __restrict__ cvals, int* __restrict__ wflag,
    int* __restrict__ flagP, int* __restrict__ flag1, int* __restrict__ flag2)
{
    const int pair = (blockIdx.x << 2) + (threadIdx.x >> 6);
    const int lane = threadIdx.x & 63;
    const int b = pair / 3;
    const int f = idxv[pair];
    const float a = vals[pair];
    const float* xb = x + (size_t)b * D_DIM;
    const float* w1 = We1 + (size_t)f * D_DIM;
    const float* w2 = We2 + (size_t)f * D_DIM;
    float s1 = 0.f, s2 = 0.f;
#pragma unroll
    for (int m = 0; m < 8; ++m) {
        int e = lane + (m << 6);
        float xv = xb[e];
        s1 = fmaf(xv, w1[e], s1);
        s2 = fmaf(xv, w2[e], s2);
    }
#pragma unroll
    for (int m = 1; m < 64; m <<= 1) { s1 += __shfl_xor(s1, m); s2 += __shfl_xor(s2, m); }
    if (lane == 0) {
        float p1v = s1 + be1[f];
        float p2v = s2 + be2[f];
        float m1 = (a != 0.f) ? p1v : 0.f;
        float m2 = (a != 0.f) ? p2v : 0.f;
        bool win = m1 > m2;
        float fa1 = win ? m1 : 0.f;
        float fa2 = win ? 0.f : m2;
        cvals[pair] = win ? fa1 : fa2;
        wflag[pair] = win ? 1 : 0;
        flagP[f] = 1;
        if (fa1 != 0.f) flag1[f] = 1;
        if (fa2 != 0.f) flag2[f] = 1;
    }
}

// ---------------------------------------------------------------------------
// Kernel 6: recon from transposed bf16 decoders (coalesced row reads)
// ---------------------------------------------------------------------------
__global__ __launch_bounds__(512) void recon_kernel(
    const ushort* __restrict__ WdT, const float* __restrict__ bd,
    const ushort* __restrict__ Wd1T, const float* __restrict__ bd1,
    const ushort* __restrict__ Wd2T, const float* __restrict__ bd2,
    const float* __restrict__ vals, const int* __restrict__ idxv,
    const float* __restrict__ cvals, const int* __restrict__ wflag,
    float* __restrict__ out)
{
    const int b = blockIdx.x;
    const int d = threadIdx.x;
    float o = bd[d] + bd1[d] + bd2[d];
#pragma unroll
    for (int k = 0; k < 3; ++k) {
        const int p = b * 3 + k;
        const int f = idxv[p];
        const float a = vals[p];
        const float c = cvals[p];
        const int win = wflag[p];
        const size_t off = (size_t)f * D_DIM + d;
        o = fmaf(a, __uint_as_float((uint)WdT[off] << 16), o);
        if (c != 0.f) {
            const ushort* wt = win ? Wd1T : Wd2T;
            o = fmaf(c, __uint_as_float((uint)wt[off] << 16), o);
        }
    }
    out[(size_t)b * D_DIM + d] = o;
}

// ---------------------------------------------------------------------------
// Kernel 7: aux cosine terms per pair; deterministic per-block partials
// ---------------------------------------------------------------------------
__global__ __launch_bounds__(256) void aux_kernel(
    const float* __restrict__ vals, const float* __restrict__ cvals,
    const int* __restrict__ wflag, const int* __restrict__ idxv,
    const float* __restrict__ gram,
    float* __restrict__ auxpart, float* __restrict__ cntpart)
{
    const int p = blockIdx.x * 256 + threadIdx.x;
    float term = 0.f, act = 0.f;
    {
        const float a = vals[p];
        const float c = cvals[p];
        const int win = wflag[p];
        const int f = idxv[p];
        const float pp = gram[f];
        const float pc = win ? gram[F_DIM + f] : gram[2 * F_DIM + f];
        const float cc = win ? gram[3 * F_DIM + f] : gram[4 * F_DIM + f];
        const float dot = a * (a * pp + c * pc);
        const float nx = fabsf(a) * sqrtf(pp);
        const float ny2 = a * a * pp + 2.f * a * c * pc + c * c * cc;
        const float ny = sqrtf(fmaxf(ny2, 0.f));
        const float cosv = dot / (fmaxf(nx, 1e-8f) * fmaxf(ny, 1e-8f));
        if (a > 0.f) { act = 1.f; term = fmaxf(0.f, 0.7f - cosv); }
    }
#pragma unroll
    for (int m = 1; m < 64; m <<= 1) { term += __shfl_xor(term, m); act += __shfl_xor(act, m); }
    __shared__ float st[2][4];
    const int w = threadIdx.x >> 6;
    if ((threadIdx.x & 63) == 0) { st[0][w] = term; st[1][w] = act; }
    __syncthreads();
    if (threadIdx.x == 0) {
        auxpart[blockIdx.x] = st[0][0] + st[0][1] + st[0][2] + st[0][3];
        cntpart[blockIdx.x] = st[1][0] + st[1][1] + st[1][2] + st[1][3];
    }
}

// ---------------------------------------------------------------------------
// Kernel 8: count flags, finish aux, write scalar outputs (as f32)
// ---------------------------------------------------------------------------
__global__ __launch_bounds__(256) void finalize_kernel(
    const int* __restrict__ flagP, const int* __restrict__ flag1,
    const int* __restrict__ flag2,
    const float* __restrict__ auxpart, const float* __restrict__ cntpart,
    float* __restrict__ out)
{
    const int t = threadIdx.x;
    int sp = 0, s1 = 0, s2 = 0;
    for (int f = t; f < F_DIM; f += 256) { sp += flagP[f]; s1 += flag1[f]; s2 += flag2[f]; }
#pragma unroll
    for (int m = 1; m < 64; m <<= 1) {
        sp += __shfl_xor(sp, m); s1 += __shfl_xor(s1, m); s2 += __shfl_xor(s2, m);
    }
    __shared__ int red[3][4];
    const int w = t >> 6;
    if ((t & 63) == 0) { red[0][w] = sp; red[1][w] = s1; red[2][w] = s2; }
    __syncthreads();
    if (t == 0) {
        float np_ = (float)(red[0][0] + red[0][1] + red[0][2] + red[0][3]);
        float n1_ = (float)(red[1][0] + red[1][1] + red[1][2] + red[1][3]);
        float n2_ = (float)(red[2][0] + red[2][1] + red[2][2] + red[2][3]);
        float asum = 0.f, acnt = 0.f;
        for (int i = 0; i < 24; ++i) { asum += auxpart[i]; acnt += cntpart[i]; }
        const size_t base = (size_t)B_DIM * D_DIM;
        out[base + 0] = np_;
        out[base + 1] = n1_;
        out[base + 2] = n2_;
        out[base + 3] = asum / (acnt + 1e-8f);
    }
}

extern "C" void kernel_launch(void* const* d_in, const int* in_sizes, int n_in,
                              void* d_out, int out_size, void* d_ws, size_t ws_size,
                              hipStream_t stream)
{
    (void)in_sizes; (void)n_in; (void)out_size; (void)ws_size;
    const float* x   = (const float*)d_in[0];
    const float* We  = (const float*)d_in[1];
    const float* be  = (const float*)d_in[2];
    const float* Wd  = (const float*)d_in[3];
    const float* bd  = (const float*)d_in[4];
    const float* We1 = (const float*)d_in[5];
    const float* be1 = (const float*)d_in[6];
    const float* Wd1 = (const float*)d_in[7];
    const float* bd1 = (const float*)d_in[8];
    const float* We2 = (const float*)d_in[9];
    const float* be2 = (const float*)d_in[10];
    const float* Wd2 = (const float*)d_in[11];
    const float* bd2 = (const float*)d_in[12];
    float* out = (float*)d_out;

    // workspace layout (~73 MB)
    ushort* x_bf  = (ushort*)d_ws;                             // B*D
    ushort* We_bf = x_bf + (size_t)B_DIM * D_DIM;              // F*D
    ushort* WdT   = We_bf + (size_t)F_DIM * D_DIM;             // F*D
    ushort* Wd1T  = WdT + (size_t)F_DIM * D_DIM;               // F*D
    ushort* Wd2T  = Wd1T + (size_t)F_DIM * D_DIM;              // F*D
    uint*   packed = (uint*)(Wd2T + (size_t)F_DIM * D_DIM);    // B*768
    float*  gram  = (float*)(packed + (size_t)B_DIM * 768);    // 5F
    int*    flagP = (int*)(gram + 5 * F_DIM);                  // F
    int*    flag1 = flagP + F_DIM;                             // F
    int*    flag2 = flag1 + F_DIM;                             // F
    int*    c8i   = flag2 + F_DIM;                             // B*8
    float*  vals  = (float*)(c8i + B_DIM * 8);                 // B*3
    int*    idxv  = (int*)(vals + B_DIM * 3);                  // B*3
    float*  cvals = (float*)(idxv + B_DIM * 3);                // B*3
    int*    wflag = (int*)(cvals + B_DIM * 3);                 // B*3
    float*  auxpart = (float*)(wflag + B_DIM * 3);             // 24
    float*  cntpart = auxpart + 24;                            // 24

    hipMemsetAsync(flagP, 0, 3 * F_DIM * sizeof(int), stream);

    convert_kernel<<<2048, 256, 0, stream>>>(We, We_bf, F_DIM * D_DIM / 8);
    convert_kernel<<<256, 256, 0, stream>>>(x, x_bf, B_DIM * D_DIM / 8);

    dim3 g1(F_DIM / 128, B_DIM / 128);  // 128 x 16
    gemm_kernel<<<g1, 256, 0, stream>>>(x_bf, We_bf, be, packed);
    merge_kernel<<<B_DIM, 64, 0, stream>>>(packed, c8i);
    refine_kernel<<<B_DIM, 512, 0, stream>>>(x, We, be, c8i, vals, idxv);

    trgram_kernel<<<F_DIM / 64, 512, 0, stream>>>(
        Wd, Wd1, Wd2, WdT, Wd1T, Wd2T, gram);
    child_kernel<<<(B_DIM * K_TOP) / 4, 256, 0, stream>>>(
        x, We1, be1, We2, be2, vals, idxv, cvals, wflag, flagP, flag1, flag2);
    recon_kernel<<<B_DIM, 512, 0, stream>>>(
        WdT, bd, Wd1T, bd1, Wd2T, bd2, vals, idxv, cvals, wflag, out);
    aux_kernel<<<(B_DIM * K_TOP) / 256, 256, 0, stream>>>(
        vals, cvals, wflag, idxv, gram, auxpart, cntpart);
    finalize_kernel<<<1, 256, 0, stream>>>(flagP, flag1, flag2, auxpart, cntpart, out);
}